// Round 1
// baseline (4341.899 us; speedup 1.0000x reference)
//
#include <hip/hip_runtime.h>
#include <math.h>

#define N_NODES_C 100000
#define N_EDGES_C 1600000
#define IN_DIM_C 64
#define HID_C 128
#define N_ASSETS_C 50
#define N_GRAPHS_C 64

// ---------------------------------------------------------------------------
// Scatter-add of feature rows over edges: agg[dst] += feat[src]
// One thread per (edge, float4-chunk). W = feature width (64 or 128).
// ---------------------------------------------------------------------------
template<int W>
__global__ __launch_bounds__(256) void scatter_kernel(
    const float* __restrict__ feat, const int* __restrict__ ei,
    float* __restrict__ agg)
{
    constexpr int CH = W / 4;  // float4 chunks per row (16 or 32), power of 2
    unsigned gid = blockIdx.x * 256u + threadIdx.x;
    int e = (int)(gid / CH);
    int c = (int)(gid % CH) * 4;
    if (e >= N_EDGES_C) return;
    int src = ei[e];
    int dst = ei[N_EDGES_C + e];
    float4 v = *(const float4*)(feat + (size_t)src * W + c);
    float* p = agg + (size_t)dst * W + c;
    atomicAdd(p + 0, v.x);
    atomicAdd(p + 1, v.y);
    atomicAdd(p + 2, v.z);
    atomicAdd(p + 3, v.w);
}

// ---------------------------------------------------------------------------
// Fused GraphConv projection: out = relu(A @ Wr + X @ Wo + bias)
// A,X: [N,K], Wr,Wo: [K,128], out: [N,128].
// Block: 256 threads, 64 nodes. Thread (ng=t&15, cg=t>>4) computes a
// 4-node x 8-col register tile. K staged in 32-chunks through LDS.
// ---------------------------------------------------------------------------
template<int K>
__global__ __launch_bounds__(256) void conv_kernel(
    const float* __restrict__ A, const float* __restrict__ X,
    const float* __restrict__ Wr, const float* __restrict__ Wo,
    const float* __restrict__ bias, float* __restrict__ out, int N)
{
    constexpr int KC = 32;
    __shared__ float sWr[KC][HID_C];
    __shared__ float sWo[KC][HID_C];
    __shared__ float sA[64][33];   // +1 pad: node-stride 33 -> conflict-free
    __shared__ float sX[64][33];

    const int t  = threadIdx.x;
    const int ng = t & 15;     // node group: nodes ng*4 .. ng*4+3
    const int cg = t >> 4;     // col group: cols cg*8 .. cg*8+7
    const int n0 = blockIdx.x * 64;
    const int c0 = cg * 8;

    float acc[4][8];
#pragma unroll
    for (int i = 0; i < 4; ++i)
#pragma unroll
        for (int j = 0; j < 8; ++j) acc[i][j] = 0.f;

    for (int kc = 0; kc < K; kc += KC) {
        __syncthreads();
        // stage weight chunk: 32x128 floats each = 1024 float4s; 4 per thread
#pragma unroll
        for (int m = 0; m < 4; ++m) {
            int f  = t + m * 256;        // float4 id 0..1023
            int kk = f >> 5;             // row within chunk
            int cc = (f & 31) << 2;      // col
            *(float4*)&sWr[kk][cc] = *(const float4*)(Wr + (size_t)(kc + kk) * HID_C + cc);
            *(float4*)&sWo[kk][cc] = *(const float4*)(Wo + (size_t)(kc + kk) * HID_C + cc);
        }
        // stage input chunk: 64 nodes x 32 k = 512 float4s; 2 per thread
#pragma unroll
        for (int m = 0; m < 2; ++m) {
            int f  = t + m * 256;        // 0..511
            int n  = f >> 3;             // local node
            int kk = (f & 7) << 2;
            int node = n0 + n;
            float4 va = make_float4(0.f, 0.f, 0.f, 0.f);
            float4 vx = make_float4(0.f, 0.f, 0.f, 0.f);
            if (node < N) {
                va = *(const float4*)(A + (size_t)node * K + kc + kk);
                vx = *(const float4*)(X + (size_t)node * K + kc + kk);
            }
            sA[n][kk] = va.x; sA[n][kk + 1] = va.y; sA[n][kk + 2] = va.z; sA[n][kk + 3] = va.w;
            sX[n][kk] = vx.x; sX[n][kk + 1] = vx.y; sX[n][kk + 2] = vx.z; sX[n][kk + 3] = vx.w;
        }
        __syncthreads();

        for (int kk = 0; kk < KC; ++kk) {
            float4 wr0 = *(const float4*)&sWr[kk][c0];
            float4 wr1 = *(const float4*)&sWr[kk][c0 + 4];
            float4 wo0 = *(const float4*)&sWo[kk][c0];
            float4 wo1 = *(const float4*)&sWo[kk][c0 + 4];
#pragma unroll
            for (int i = 0; i < 4; ++i) {
                float a  = sA[ng * 4 + i][kk];
                float xv = sX[ng * 4 + i][kk];
                acc[i][0] = fmaf(a, wr0.x, fmaf(xv, wo0.x, acc[i][0]));
                acc[i][1] = fmaf(a, wr0.y, fmaf(xv, wo0.y, acc[i][1]));
                acc[i][2] = fmaf(a, wr0.z, fmaf(xv, wo0.z, acc[i][2]));
                acc[i][3] = fmaf(a, wr0.w, fmaf(xv, wo0.w, acc[i][3]));
                acc[i][4] = fmaf(a, wr1.x, fmaf(xv, wo1.x, acc[i][4]));
                acc[i][5] = fmaf(a, wr1.y, fmaf(xv, wo1.y, acc[i][5]));
                acc[i][6] = fmaf(a, wr1.z, fmaf(xv, wo1.z, acc[i][6]));
                acc[i][7] = fmaf(a, wr1.w, fmaf(xv, wo1.w, acc[i][7]));
            }
        }
    }

    const float4 bb0 = *(const float4*)(bias + c0);
    const float4 bb1 = *(const float4*)(bias + c0 + 4);
#pragma unroll
    for (int i = 0; i < 4; ++i) {
        int node = n0 + ng * 4 + i;
        if (node < N) {
            float4 o0, o1;
            o0.x = fmaxf(acc[i][0] + bb0.x, 0.f);
            o0.y = fmaxf(acc[i][1] + bb0.y, 0.f);
            o0.z = fmaxf(acc[i][2] + bb0.z, 0.f);
            o0.w = fmaxf(acc[i][3] + bb0.w, 0.f);
            o1.x = fmaxf(acc[i][4] + bb1.x, 0.f);
            o1.y = fmaxf(acc[i][5] + bb1.y, 0.f);
            o1.z = fmaxf(acc[i][6] + bb1.z, 0.f);
            o1.w = fmaxf(acc[i][7] + bb1.w, 0.f);
            *(float4*)(out + (size_t)node * HID_C + c0)     = o0;
            *(float4*)(out + (size_t)node * HID_C + c0 + 4) = o1;
        }
    }
}

// ---------------------------------------------------------------------------
// Mean-pool partials: batch is sorted, so each block run-length-compresses
// its 128 nodes into few atomics per graph.
// ---------------------------------------------------------------------------
__global__ __launch_bounds__(128) void pool_kernel(
    const float* __restrict__ h, const int* __restrict__ batch,
    float* __restrict__ pooled, float* __restrict__ cnts, int N)
{
    int j  = threadIdx.x;          // feature col 0..127
    int n0 = blockIdx.x * 128;
    int nend = min(n0 + 128, N);
    int cur = -1;
    float sum = 0.f, cnt = 0.f;
    for (int n = n0; n < nend; ++n) {
        int g = batch[n];
        if (g != cur) {
            if (cur >= 0) {
                atomicAdd(&pooled[cur * HID_C + j], sum);
                if (j == 0) atomicAdd(&cnts[cur], cnt);
            }
            cur = g; sum = 0.f; cnt = 0.f;
        }
        sum += h[(size_t)n * HID_C + j];
        cnt += 1.f;
    }
    if (cur >= 0) {
        atomicAdd(&pooled[cur * HID_C + j], sum);
        if (j == 0) atomicAdd(&cnts[cur], cnt);
    }
}

// ---------------------------------------------------------------------------
// Head: mean, fc1+relu, fc2, softmax. One block per graph.
// ---------------------------------------------------------------------------
__global__ __launch_bounds__(128) void head_kernel(
    const float* __restrict__ pooled, const float* __restrict__ cnts,
    const float* __restrict__ fc1w, const float* __restrict__ fc1b,
    const float* __restrict__ fc2w, const float* __restrict__ fc2b,
    float* __restrict__ out)
{
    __shared__ float sp[HID_C];
    __shared__ float so[HID_C];
    __shared__ float sl[64];
    __shared__ float sred[2];
    int g = blockIdx.x;
    int j = threadIdx.x;

    float inv = 1.f / fmaxf(cnts[g], 1.f);
    sp[j] = pooled[g * HID_C + j] * inv;
    __syncthreads();

    float a = fc1b[j];
    for (int k = 0; k < HID_C; ++k) a = fmaf(sp[k], fc1w[k * HID_C + j], a);
    so[j] = fmaxf(a, 0.f);
    __syncthreads();

    if (j < N_ASSETS_C) {
        float l = fc2b[j];
        for (int k = 0; k < HID_C; ++k) l = fmaf(so[k], fc2w[k * N_ASSETS_C + j], l);
        sl[j] = l;
    }
    __syncthreads();

    if (j == 0) {
        float m = -1e30f;
        for (int q = 0; q < N_ASSETS_C; ++q) m = fmaxf(m, sl[q]);
        sred[0] = m;
    }
    __syncthreads();
    if (j < N_ASSETS_C) sl[j] = expf(sl[j] - sred[0]);
    __syncthreads();
    if (j == 0) {
        float s = 0.f;
        for (int q = 0; q < N_ASSETS_C; ++q) s += sl[q];
        sred[1] = 1.f / s;
    }
    __syncthreads();
    if (j < N_ASSETS_C) out[g * N_ASSETS_C + j] = sl[j] * sred[1];
}

// ---------------------------------------------------------------------------
extern "C" void kernel_launch(void* const* d_in, const int* in_sizes, int n_in,
                              void* d_out, int out_size, void* d_ws, size_t ws_size,
                              hipStream_t stream)
{
    const float* x       = (const float*)d_in[0];
    const int*   ei      = (const int*)d_in[1];
    const int*   batch   = (const int*)d_in[2];
    const float* w1_rel  = (const float*)d_in[3];
    const float* b1      = (const float*)d_in[4];
    const float* w1_root = (const float*)d_in[5];
    const float* w2_rel  = (const float*)d_in[6];
    const float* b2      = (const float*)d_in[7];
    const float* w2_root = (const float*)d_in[8];
    const float* fc1w    = (const float*)d_in[9];
    const float* fc1b    = (const float*)d_in[10];
    const float* fc2w    = (const float*)d_in[11];
    const float* fc2b    = (const float*)d_in[12];
    float* out = (float*)d_out;

    char* ws = (char*)d_ws;
    // Workspace layout (16B-aligned offsets):
    //   agg1   [100000 x  64] f32  @ 0          (25,600,000 B)
    //   agg2   [100000 x 128] f32  @ 25,600,000 (51,200,000 B)
    //   pooled [64 x 128]     f32  @ 76,800,000 (32,768 B)
    //   cnts   [64]           f32  @ 76,832,768 (256 B)
    //   h1     [100000 x 128] f32  @ 76,833,024 (51,200,000 B)
    //   h2     [100000 x 128] f32  @ 128,033,024 (51,200,000 B)
    float* agg1   = (float*)(ws + 0);
    float* agg2   = (float*)(ws + 25600000);
    float* pooled = (float*)(ws + 76800000);
    float* cnts   = (float*)(ws + 76832768);
    float* h1     = (float*)(ws + 76833024);
    float* h2     = (float*)(ws + 128033024);

    // zero agg1 + agg2 + pooled + cnts in one shot
    hipMemsetAsync(d_ws, 0, 76833024, stream);

    // Layer 1: agg1 = scatter_add(x[src] -> dst), h1 = relu(agg1@W1r + x@W1o + b1)
    {
        int grid = (N_EDGES_C * (IN_DIM_C / 4) + 255) / 256;   // 100000
        scatter_kernel<IN_DIM_C><<<grid, 256, 0, stream>>>(x, ei, agg1);
        int cgrid = (N_NODES_C + 63) / 64;                      // 1563
        conv_kernel<IN_DIM_C><<<cgrid, 256, 0, stream>>>(agg1, x, w1_rel, w1_root, b1, h1, N_NODES_C);
    }

    // Layer 2: agg2 = scatter_add(h1[src] -> dst), h2 = relu(agg2@W2r + h1@W2o + b2)
    {
        int grid = (N_EDGES_C * (HID_C / 4) + 255) / 256;      // 200000
        scatter_kernel<HID_C><<<grid, 256, 0, stream>>>(h1, ei, agg2);
        int cgrid = (N_NODES_C + 63) / 64;
        conv_kernel<HID_C><<<cgrid, 256, 0, stream>>>(agg2, h1, w2_rel, w2_root, b2, h2, N_NODES_C);
    }

    // Pool + head
    {
        int pgrid = (N_NODES_C + 127) / 128;                    // 782
        pool_kernel<<<pgrid, 128, 0, stream>>>(h2, batch, pooled, cnts, N_NODES_C);
        head_kernel<<<N_GRAPHS_C, 128, 0, stream>>>(pooled, cnts, fc1w, fc1b, fc2w, fc2b, out);
    }
}

// Round 2
// 704.633 us; speedup vs baseline: 6.1619x; 6.1619x over previous
//
#include <hip/hip_runtime.h>
#include <math.h>

#define N_NODES_C 100000
#define N_EDGES_C 1600000
#define IN_DIM_C 64
#define HID_C 128
#define N_ASSETS_C 50
#define N_GRAPHS_C 64

#define SCAN_TILE 1024
#define SCAN_NB ((N_NODES_C + SCAN_TILE - 1) / SCAN_TILE)   // 98

// ---------------------------------------------------------------------------
// CSR build: histogram of dst, hierarchical exclusive scan, bucket fill.
// ---------------------------------------------------------------------------
__global__ __launch_bounds__(256) void hist_kernel(
    const int* __restrict__ ei, int* __restrict__ deg)
{
    int e = blockIdx.x * 256 + threadIdx.x;
    if (e < N_EDGES_C) atomicAdd(&deg[ei[N_EDGES_C + e]], 1);
}

__global__ __launch_bounds__(256) void scan_sum_kernel(
    const int* __restrict__ deg, int* __restrict__ bsum)
{
    __shared__ int sdata[256];
    int b = blockIdx.x, t = threadIdx.x;
    int base = b * SCAN_TILE + t * 4;
    int s = 0;
#pragma unroll
    for (int i = 0; i < 4; ++i) {
        int idx = base + i;
        if (idx < N_NODES_C) s += deg[idx];
    }
    sdata[t] = s;
    __syncthreads();
    for (int o = 128; o > 0; o >>= 1) {
        if (t < o) sdata[t] += sdata[t + o];
        __syncthreads();
    }
    if (t == 0) bsum[b] = sdata[0];
}

__global__ __launch_bounds__(64) void scan_top_kernel(
    const int* __restrict__ bsum, int* __restrict__ boff)
{
    if (threadIdx.x == 0) {
        int acc = 0;
        for (int i = 0; i < SCAN_NB; ++i) { boff[i] = acc; acc += bsum[i]; }
    }
}

__global__ __launch_bounds__(256) void scan_fin_kernel(
    const int* __restrict__ deg, const int* __restrict__ boff,
    int* __restrict__ row_ptr, int* __restrict__ cursor)
{
    __shared__ int sdata[256];
    int b = blockIdx.x, t = threadIdx.x;
    int base = b * SCAN_TILE + t * 4;
    int v[4];
    int s = 0;
#pragma unroll
    for (int i = 0; i < 4; ++i) {
        int idx = base + i;
        v[i] = (idx < N_NODES_C) ? deg[idx] : 0;
        s += v[i];
    }
    sdata[t] = s;
    __syncthreads();
    // Hillis-Steele inclusive scan over 256 thread sums
    for (int o = 1; o < 256; o <<= 1) {
        int x = (t >= o) ? sdata[t - o] : 0;
        __syncthreads();
        sdata[t] += x;
        __syncthreads();
    }
    int run = boff[b] + sdata[t] - s;   // exclusive prefix of this thread's chunk
#pragma unroll
    for (int i = 0; i < 4; ++i) {
        int idx = base + i;
        if (idx < N_NODES_C) { row_ptr[idx] = run; cursor[idx] = run; }
        run += v[i];
    }
    if (b == 0 && t == 0) row_ptr[N_NODES_C] = N_EDGES_C;
}

__global__ __launch_bounds__(256) void fill_kernel(
    const int* __restrict__ ei, int* __restrict__ cursor, int* __restrict__ col)
{
    int e = blockIdx.x * 256 + threadIdx.x;
    if (e < N_EDGES_C) {
        int dst = ei[N_EDGES_C + e];
        int p = atomicAdd(&cursor[dst], 1);
        col[p] = ei[e];
    }
}

// ---------------------------------------------------------------------------
// CSR gather-aggregate: agg[n] = sum_{e in in(n)} feat[col[e]]
// One wave per node; lane covers W/64 consecutive floats. No atomics;
// each agg row written exactly once.
// ---------------------------------------------------------------------------
template<int W>
__global__ __launch_bounds__(256) void gather_kernel(
    const float* __restrict__ feat, const int* __restrict__ row_ptr,
    const int* __restrict__ col, float* __restrict__ agg)
{
    int wave = threadIdx.x >> 6;
    int lane = threadIdx.x & 63;
    int n = blockIdx.x * 4 + wave;
    if (n >= N_NODES_C) return;
    int beg = row_ptr[n];
    int end = row_ptr[n + 1];
    if (W == 128) {
        const float2* f2 = (const float2*)feat;
        float sx = 0.f, sy = 0.f;
        int e = beg;
        for (; e + 1 < end; e += 2) {
            int a = col[e], b = col[e + 1];
            float2 va = f2[(size_t)a * 64 + lane];
            float2 vb = f2[(size_t)b * 64 + lane];
            sx += va.x + vb.x;
            sy += va.y + vb.y;
        }
        if (e < end) {
            float2 v = f2[(size_t)col[e] * 64 + lane];
            sx += v.x; sy += v.y;
        }
        ((float2*)agg)[(size_t)n * 64 + lane] = make_float2(sx, sy);
    } else {
        float s = 0.f;
        int e = beg;
        for (; e + 1 < end; e += 2) {
            int a = col[e], b = col[e + 1];
            s += feat[(size_t)a * W + lane] + feat[(size_t)b * W + lane];
        }
        if (e < end) s += feat[(size_t)col[e] * W + lane];
        agg[(size_t)n * W + lane] = s;
    }
}

// ---------------------------------------------------------------------------
// Fused GraphConv projection: out = relu(A @ Wr + X @ Wo + bias)
// ---------------------------------------------------------------------------
template<int K>
__global__ __launch_bounds__(256) void conv_kernel(
    const float* __restrict__ A, const float* __restrict__ X,
    const float* __restrict__ Wr, const float* __restrict__ Wo,
    const float* __restrict__ bias, float* __restrict__ out, int N)
{
    constexpr int KC = 32;
    __shared__ float sWr[KC][HID_C];
    __shared__ float sWo[KC][HID_C];
    __shared__ float sA[64][33];
    __shared__ float sX[64][33];

    const int t  = threadIdx.x;
    const int ng = t & 15;
    const int cg = t >> 4;
    const int n0 = blockIdx.x * 64;
    const int c0 = cg * 8;

    float acc[4][8];
#pragma unroll
    for (int i = 0; i < 4; ++i)
#pragma unroll
        for (int j = 0; j < 8; ++j) acc[i][j] = 0.f;

    for (int kc = 0; kc < K; kc += KC) {
        __syncthreads();
#pragma unroll
        for (int m = 0; m < 4; ++m) {
            int f  = t + m * 256;
            int kk = f >> 5;
            int cc = (f & 31) << 2;
            *(float4*)&sWr[kk][cc] = *(const float4*)(Wr + (size_t)(kc + kk) * HID_C + cc);
            *(float4*)&sWo[kk][cc] = *(const float4*)(Wo + (size_t)(kc + kk) * HID_C + cc);
        }
#pragma unroll
        for (int m = 0; m < 2; ++m) {
            int f  = t + m * 256;
            int n  = f >> 3;
            int kk = (f & 7) << 2;
            int node = n0 + n;
            float4 va = make_float4(0.f, 0.f, 0.f, 0.f);
            float4 vx = make_float4(0.f, 0.f, 0.f, 0.f);
            if (node < N) {
                va = *(const float4*)(A + (size_t)node * K + kc + kk);
                vx = *(const float4*)(X + (size_t)node * K + kc + kk);
            }
            sA[n][kk] = va.x; sA[n][kk + 1] = va.y; sA[n][kk + 2] = va.z; sA[n][kk + 3] = va.w;
            sX[n][kk] = vx.x; sX[n][kk + 1] = vx.y; sX[n][kk + 2] = vx.z; sX[n][kk + 3] = vx.w;
        }
        __syncthreads();

        for (int kk = 0; kk < KC; ++kk) {
            float4 wr0 = *(const float4*)&sWr[kk][c0];
            float4 wr1 = *(const float4*)&sWr[kk][c0 + 4];
            float4 wo0 = *(const float4*)&sWo[kk][c0];
            float4 wo1 = *(const float4*)&sWo[kk][c0 + 4];
#pragma unroll
            for (int i = 0; i < 4; ++i) {
                float a  = sA[ng * 4 + i][kk];
                float xv = sX[ng * 4 + i][kk];
                acc[i][0] = fmaf(a, wr0.x, fmaf(xv, wo0.x, acc[i][0]));
                acc[i][1] = fmaf(a, wr0.y, fmaf(xv, wo0.y, acc[i][1]));
                acc[i][2] = fmaf(a, wr0.z, fmaf(xv, wo0.z, acc[i][2]));
                acc[i][3] = fmaf(a, wr0.w, fmaf(xv, wo0.w, acc[i][3]));
                acc[i][4] = fmaf(a, wr1.x, fmaf(xv, wo1.x, acc[i][4]));
                acc[i][5] = fmaf(a, wr1.y, fmaf(xv, wo1.y, acc[i][5]));
                acc[i][6] = fmaf(a, wr1.z, fmaf(xv, wo1.z, acc[i][6]));
                acc[i][7] = fmaf(a, wr1.w, fmaf(xv, wo1.w, acc[i][7]));
            }
        }
    }

    const float4 bb0 = *(const float4*)(bias + c0);
    const float4 bb1 = *(const float4*)(bias + c0 + 4);
#pragma unroll
    for (int i = 0; i < 4; ++i) {
        int node = n0 + ng * 4 + i;
        if (node < N) {
            float4 o0, o1;
            o0.x = fmaxf(acc[i][0] + bb0.x, 0.f);
            o0.y = fmaxf(acc[i][1] + bb0.y, 0.f);
            o0.z = fmaxf(acc[i][2] + bb0.z, 0.f);
            o0.w = fmaxf(acc[i][3] + bb0.w, 0.f);
            o1.x = fmaxf(acc[i][4] + bb1.x, 0.f);
            o1.y = fmaxf(acc[i][5] + bb1.y, 0.f);
            o1.z = fmaxf(acc[i][6] + bb1.z, 0.f);
            o1.w = fmaxf(acc[i][7] + bb1.w, 0.f);
            *(float4*)(out + (size_t)node * HID_C + c0)     = o0;
            *(float4*)(out + (size_t)node * HID_C + c0 + 4) = o1;
        }
    }
}

// ---------------------------------------------------------------------------
// Mean-pool partials over sorted batch ids.
// ---------------------------------------------------------------------------
__global__ __launch_bounds__(128) void pool_kernel(
    const float* __restrict__ h, const int* __restrict__ batch,
    float* __restrict__ pooled, float* __restrict__ cnts, int N)
{
    int j  = threadIdx.x;
    int n0 = blockIdx.x * 128;
    int nend = min(n0 + 128, N);
    int cur = -1;
    float sum = 0.f, cnt = 0.f;
    for (int n = n0; n < nend; ++n) {
        int g = batch[n];
        if (g != cur) {
            if (cur >= 0) {
                atomicAdd(&pooled[cur * HID_C + j], sum);
                if (j == 0) atomicAdd(&cnts[cur], cnt);
            }
            cur = g; sum = 0.f; cnt = 0.f;
        }
        sum += h[(size_t)n * HID_C + j];
        cnt += 1.f;
    }
    if (cur >= 0) {
        atomicAdd(&pooled[cur * HID_C + j], sum);
        if (j == 0) atomicAdd(&cnts[cur], cnt);
    }
}

// ---------------------------------------------------------------------------
// Head: mean, fc1+relu, fc2, softmax. One block per graph.
// ---------------------------------------------------------------------------
__global__ __launch_bounds__(128) void head_kernel(
    const float* __restrict__ pooled, const float* __restrict__ cnts,
    const float* __restrict__ fc1w, const float* __restrict__ fc1b,
    const float* __restrict__ fc2w, const float* __restrict__ fc2b,
    float* __restrict__ out)
{
    __shared__ float sp[HID_C];
    __shared__ float so[HID_C];
    __shared__ float sl[64];
    __shared__ float sred[2];
    int g = blockIdx.x;
    int j = threadIdx.x;

    float inv = 1.f / fmaxf(cnts[g], 1.f);
    sp[j] = pooled[g * HID_C + j] * inv;
    __syncthreads();

    float a = fc1b[j];
    for (int k = 0; k < HID_C; ++k) a = fmaf(sp[k], fc1w[k * HID_C + j], a);
    so[j] = fmaxf(a, 0.f);
    __syncthreads();

    if (j < N_ASSETS_C) {
        float l = fc2b[j];
        for (int k = 0; k < HID_C; ++k) l = fmaf(so[k], fc2w[k * N_ASSETS_C + j], l);
        sl[j] = l;
    }
    __syncthreads();

    if (j == 0) {
        float m = -1e30f;
        for (int q = 0; q < N_ASSETS_C; ++q) m = fmaxf(m, sl[q]);
        sred[0] = m;
    }
    __syncthreads();
    if (j < N_ASSETS_C) sl[j] = expf(sl[j] - sred[0]);
    __syncthreads();
    if (j == 0) {
        float s = 0.f;
        for (int q = 0; q < N_ASSETS_C; ++q) s += sl[q];
        sred[1] = 1.f / s;
    }
    __syncthreads();
    if (j < N_ASSETS_C) out[g * N_ASSETS_C + j] = sl[j] * sred[1];
}

// ---------------------------------------------------------------------------
extern "C" void kernel_launch(void* const* d_in, const int* in_sizes, int n_in,
                              void* d_out, int out_size, void* d_ws, size_t ws_size,
                              hipStream_t stream)
{
    const float* x       = (const float*)d_in[0];
    const int*   ei      = (const int*)d_in[1];
    const int*   batch   = (const int*)d_in[2];
    const float* w1_rel  = (const float*)d_in[3];
    const float* b1      = (const float*)d_in[4];
    const float* w1_root = (const float*)d_in[5];
    const float* w2_rel  = (const float*)d_in[6];
    const float* b2      = (const float*)d_in[7];
    const float* w2_root = (const float*)d_in[8];
    const float* fc1w    = (const float*)d_in[9];
    const float* fc1b    = (const float*)d_in[10];
    const float* fc2w    = (const float*)d_in[11];
    const float* fc2b    = (const float*)d_in[12];
    float* out = (float*)d_out;

    char* ws = (char*)d_ws;
    // Workspace layout. Region [0, 51.2 MB) is reused: CSR scratch + agg1
    // live there early, then h2 (written by conv2, after all CSR/agg1 reads
    // are done) overlays the whole region.
    //   deg:     [0, 400000)                N int   [zeroed]
    //   row_ptr: [400000, 800016)           N+1 int
    //   cursor:  [800016, 1200016)          N int
    //   bsum:    [1200016, 1201040)         256 int
    //   boff:    [1201040, 1202064)         256 int
    //   col:     [1202064, 7602064)         E int
    //   agg1:    [7602064, 33202064)        N x 64 f32
    //   h2:      [0, 51200000)              N x 128 f32   (overlay)
    //   agg2:    [51200000, 102400000)      N x 128 f32
    //   h1:      [102400000, 153600000)     N x 128 f32
    //   pooled:  [153600000, 153632768)     64 x 128 f32  [zeroed]
    //   cnts:    [153632768, 153633024)     64 f32        [zeroed]
    int*   deg     = (int*)(ws + 0);
    int*   row_ptr = (int*)(ws + 400000);
    int*   cursor  = (int*)(ws + 800016);
    int*   bsum    = (int*)(ws + 1200016);
    int*   boff    = (int*)(ws + 1201040);
    int*   col     = (int*)(ws + 1202064);
    float* agg1    = (float*)(ws + 7602064);
    float* h2      = (float*)(ws + 0);
    float* agg2    = (float*)(ws + 51200000);
    float* h1      = (float*)(ws + 102400000);
    float* pooled  = (float*)(ws + 153600000);
    float* cnts    = (float*)(ws + 153632768);

    hipMemsetAsync(deg, 0, 400000, stream);
    hipMemsetAsync(pooled, 0, 33024, stream);

    // ---- CSR build (shared by both layers) ----
    const int egrid = (N_EDGES_C + 255) / 256;   // 6250
    hist_kernel<<<egrid, 256, 0, stream>>>(ei, deg);
    scan_sum_kernel<<<SCAN_NB, 256, 0, stream>>>(deg, bsum);
    scan_top_kernel<<<1, 64, 0, stream>>>(bsum, boff);
    scan_fin_kernel<<<SCAN_NB, 256, 0, stream>>>(deg, boff, row_ptr, cursor);
    fill_kernel<<<egrid, 256, 0, stream>>>(ei, cursor, col);

    const int ggrid = (N_NODES_C + 3) / 4;       // 25000
    const int cgrid = (N_NODES_C + 63) / 64;     // 1563

    // ---- Layer 1 ----
    gather_kernel<IN_DIM_C><<<ggrid, 256, 0, stream>>>(x, row_ptr, col, agg1);
    conv_kernel<IN_DIM_C><<<cgrid, 256, 0, stream>>>(agg1, x, w1_rel, w1_root, b1, h1, N_NODES_C);

    // ---- Layer 2 ----
    gather_kernel<HID_C><<<ggrid, 256, 0, stream>>>(h1, row_ptr, col, agg2);
    conv_kernel<HID_C><<<cgrid, 256, 0, stream>>>(agg2, h1, w2_rel, w2_root, b2, h2, N_NODES_C);

    // ---- Pool + head ----
    const int pgrid = (N_NODES_C + 127) / 128;   // 782
    pool_kernel<<<pgrid, 128, 0, stream>>>(h2, batch, pooled, cnts, N_NODES_C);
    head_kernel<<<N_GRAPHS_C, 128, 0, stream>>>(pooled, cnts, fc1w, fc1b, fc2w, fc2b, out);
}

// Round 3
// 573.126 us; speedup vs baseline: 7.5758x; 1.2295x over previous
//
#include <hip/hip_runtime.h>
#include <math.h>

#define N_NODES_C 100000
#define N_EDGES_C 1600000
#define IN_DIM_C 64
#define HID_C 128
#define N_ASSETS_C 50
#define N_GRAPHS_C 64

#define BKT_SHIFT 9
#define BKT_NODES 512
#define NB_BKT ((N_NODES_C + BKT_NODES - 1) / BKT_NODES)   // 196
#define EPB_A 8192                                          // edges per pass-A block
#define NBLK_A ((N_EDGES_C + EPB_A - 1) / EPB_A)            // 196

// ---------------------------------------------------------------------------
// Bucket histogram: count edges per 512-node dst bucket.
// ---------------------------------------------------------------------------
__global__ __launch_bounds__(256) void bucket_hist_kernel(
    const int* __restrict__ ei, int* __restrict__ bcnt)
{
    __shared__ int cnt[NB_BKT];
    int t = threadIdx.x;
    for (int i = t; i < NB_BKT; i += 256) cnt[i] = 0;
    __syncthreads();
    int base = blockIdx.x * 2048;
#pragma unroll
    for (int i = 0; i < 8; ++i) {
        int e = base + i * 256 + t;
        if (e < N_EDGES_C) {
            int dst = ei[N_EDGES_C + e];
            atomicAdd(&cnt[dst >> BKT_SHIFT], 1);
        }
    }
    __syncthreads();
    for (int i = t; i < NB_BKT; i += 256)
        if (cnt[i]) atomicAdd(&bcnt[i], cnt[i]);
}

// ---------------------------------------------------------------------------
// Scan bucket counts -> bucket_base (exclusive) + init gcursor.
// ---------------------------------------------------------------------------
__global__ __launch_bounds__(256) void bucket_scan_kernel(
    const int* __restrict__ bcnt, int* __restrict__ bbase, int* __restrict__ gcur)
{
    __shared__ int s[256];
    int t = threadIdx.x;
    int v = (t < NB_BKT) ? bcnt[t] : 0;
    s[t] = v;
    __syncthreads();
    for (int o = 1; o < 256; o <<= 1) {
        int x = (t >= o) ? s[t - o] : 0;
        __syncthreads();
        s[t] += x;
        __syncthreads();
    }
    int excl = s[t] - v;
    if (t < NB_BKT) { bbase[t] = excl; gcur[t] = excl; }
    if (t == 255) bbase[NB_BKT] = s[255];   // == N_EDGES_C
}

// ---------------------------------------------------------------------------
// Pass A: bucket-partition edges into tmp with coalesced run writes.
// tmp entry: (dst & 511) << 17 | src   (src < 2^17, dstLow < 2^9)
// ---------------------------------------------------------------------------
__global__ __launch_bounds__(256) void partition_kernel(
    const int* __restrict__ ei, int* __restrict__ gcur,
    unsigned* __restrict__ tmp)
{
    __shared__ unsigned stage[EPB_A];        // 32 KB
    __shared__ unsigned stage2[EPB_A];       // 32 KB
    __shared__ unsigned char sbkt[EPB_A];    // 8 KB
    __shared__ unsigned char sbkt2[EPB_A];   // 8 KB
    __shared__ int cnt[NB_BKT];
    __shared__ int base[NB_BKT];
    __shared__ int cur[NB_BKT];
    __shared__ int gb[NB_BKT];
    __shared__ int s[256];

    const int t = threadIdx.x;
    const int e0 = blockIdx.x * EPB_A;
    const int nE = min(EPB_A, N_EDGES_C - e0);

    for (int i = t; i < NB_BKT; i += 256) cnt[i] = 0;
    __syncthreads();

    // load + pack + local histogram
    for (int idx = t; idx < nE; idx += 256) {
        int e = e0 + idx;
        int src = ei[e];
        int dst = ei[N_EDGES_C + e];
        int b = dst >> BKT_SHIFT;
        stage[idx] = ((unsigned)(dst & (BKT_NODES - 1)) << 17) | (unsigned)src;
        sbkt[idx] = (unsigned char)b;
        atomicAdd(&cnt[b], 1);
    }
    __syncthreads();

    // exclusive scan of cnt over NB_BKT (<=256)
    int v = (t < NB_BKT) ? cnt[t] : 0;
    s[t] = v;
    __syncthreads();
    for (int o = 1; o < 256; o <<= 1) {
        int x = (t >= o) ? s[t - o] : 0;
        __syncthreads();
        s[t] += x;
        __syncthreads();
    }
    if (t < NB_BKT) {
        int excl = s[t] - v;
        base[t] = excl;
        cur[t] = excl;
        gb[t] = atomicAdd(&gcur[t], v);   // reserve global span
    }
    __syncthreads();

    // local counting-sort into stage2
    for (int idx = t; idx < nE; idx += 256) {
        int b = sbkt[idx];
        int p = atomicAdd(&cur[b], 1);
        stage2[p] = stage[idx];
        sbkt2[p] = (unsigned char)b;
    }
    __syncthreads();

    // copy out: contiguous runs per bucket -> coalesced-ish global writes
    for (int idx = t; idx < nE; idx += 256) {
        int b = sbkt2[idx];
        int dest = gb[b] + (idx - base[b]);
        tmp[dest] = stage2[idx];
    }
}

// ---------------------------------------------------------------------------
// Pass B: per bucket, build row_ptr (local LDS scan) and dst-sorted col.
// All col writes land in the bucket's contiguous ~33 KB span (one block,
// one XCD L2) -> full-line write-back.
// ---------------------------------------------------------------------------
__global__ __launch_bounds__(256) void bucket_sort_kernel(
    const unsigned* __restrict__ tmp, const int* __restrict__ bbase,
    int* __restrict__ row_ptr, int* __restrict__ col)
{
    __shared__ int ldeg[BKT_NODES];   // degree, then cursor
    __shared__ int lsum[256];
    const int t = threadIdx.x;
    const int b = blockIdx.x;
    const int beg = bbase[b];
    const int end = bbase[b + 1];

    ldeg[t] = 0; ldeg[t + 256] = 0;
    __syncthreads();

    for (int p = beg + t; p < end; p += 256)
        atomicAdd(&ldeg[tmp[p] >> 17], 1);
    __syncthreads();

    // exclusive scan of 512 degrees: thread t owns pair (2t, 2t+1)
    int a0 = ldeg[2 * t], a1 = ldeg[2 * t + 1];
    int pair = a0 + a1;
    lsum[t] = pair;
    __syncthreads();
    for (int o = 1; o < 256; o <<= 1) {
        int x = (t >= o) ? lsum[t - o] : 0;
        __syncthreads();
        lsum[t] += x;
        __syncthreads();
    }
    int ep = lsum[t] - pair;     // exclusive prefix of pair
    __syncthreads();
    ldeg[2 * t] = ep;            // cursor (relative to beg)
    ldeg[2 * t + 1] = ep + a0;

    int gn0 = b * BKT_NODES + 2 * t;
    if (gn0 < N_NODES_C)     row_ptr[gn0] = beg + ep;
    if (gn0 + 1 < N_NODES_C) row_ptr[gn0 + 1] = beg + ep + a0;
    if (b == NB_BKT - 1 && t == 0) row_ptr[N_NODES_C] = N_EDGES_C;
    __syncthreads();

    for (int p = beg + t; p < end; p += 256) {
        unsigned v = tmp[p];
        int pos = atomicAdd(&ldeg[v >> 17], 1);
        col[beg + pos] = (int)(v & 0x1FFFFu);
    }
}

// ---------------------------------------------------------------------------
// CSR gather-aggregate: agg[n] = sum_{e in in(n)} feat[col[e]]
// ---------------------------------------------------------------------------
template<int W>
__global__ __launch_bounds__(256) void gather_kernel(
    const float* __restrict__ feat, const int* __restrict__ row_ptr,
    const int* __restrict__ col, float* __restrict__ agg)
{
    int wave = threadIdx.x >> 6;
    int lane = threadIdx.x & 63;
    int n = blockIdx.x * 4 + wave;
    if (n >= N_NODES_C) return;
    int beg = row_ptr[n];
    int end = row_ptr[n + 1];
    if (W == 128) {
        const float2* f2 = (const float2*)feat;
        float sx = 0.f, sy = 0.f;
        int e = beg;
        for (; e + 1 < end; e += 2) {
            int a = col[e], b = col[e + 1];
            float2 va = f2[(size_t)a * 64 + lane];
            float2 vb = f2[(size_t)b * 64 + lane];
            sx += va.x + vb.x;
            sy += va.y + vb.y;
        }
        if (e < end) {
            float2 v = f2[(size_t)col[e] * 64 + lane];
            sx += v.x; sy += v.y;
        }
        ((float2*)agg)[(size_t)n * 64 + lane] = make_float2(sx, sy);
    } else {
        float s = 0.f;
        int e = beg;
        for (; e + 1 < end; e += 2) {
            int a = col[e], b = col[e + 1];
            s += feat[(size_t)a * W + lane] + feat[(size_t)b * W + lane];
        }
        if (e < end) s += feat[(size_t)col[e] * W + lane];
        agg[(size_t)n * W + lane] = s;
    }
}

// ---------------------------------------------------------------------------
// Fused GraphConv projection: out = relu(A @ Wr + X @ Wo + bias)
// ---------------------------------------------------------------------------
template<int K>
__global__ __launch_bounds__(256) void conv_kernel(
    const float* __restrict__ A, const float* __restrict__ X,
    const float* __restrict__ Wr, const float* __restrict__ Wo,
    const float* __restrict__ bias, float* __restrict__ out, int N)
{
    constexpr int KC = 32;
    __shared__ float sWr[KC][HID_C];
    __shared__ float sWo[KC][HID_C];
    __shared__ float sA[64][33];
    __shared__ float sX[64][33];

    const int t  = threadIdx.x;
    const int ng = t & 15;
    const int cg = t >> 4;
    const int n0 = blockIdx.x * 64;
    const int c0 = cg * 8;

    float acc[4][8];
#pragma unroll
    for (int i = 0; i < 4; ++i)
#pragma unroll
        for (int j = 0; j < 8; ++j) acc[i][j] = 0.f;

    for (int kc = 0; kc < K; kc += KC) {
        __syncthreads();
#pragma unroll
        for (int m = 0; m < 4; ++m) {
            int f  = t + m * 256;
            int kk = f >> 5;
            int cc = (f & 31) << 2;
            *(float4*)&sWr[kk][cc] = *(const float4*)(Wr + (size_t)(kc + kk) * HID_C + cc);
            *(float4*)&sWo[kk][cc] = *(const float4*)(Wo + (size_t)(kc + kk) * HID_C + cc);
        }
#pragma unroll
        for (int m = 0; m < 2; ++m) {
            int f  = t + m * 256;
            int n  = f >> 3;
            int kk = (f & 7) << 2;
            int node = n0 + n;
            float4 va = make_float4(0.f, 0.f, 0.f, 0.f);
            float4 vx = make_float4(0.f, 0.f, 0.f, 0.f);
            if (node < N) {
                va = *(const float4*)(A + (size_t)node * K + kc + kk);
                vx = *(const float4*)(X + (size_t)node * K + kc + kk);
            }
            sA[n][kk] = va.x; sA[n][kk + 1] = va.y; sA[n][kk + 2] = va.z; sA[n][kk + 3] = va.w;
            sX[n][kk] = vx.x; sX[n][kk + 1] = vx.y; sX[n][kk + 2] = vx.z; sX[n][kk + 3] = vx.w;
        }
        __syncthreads();

        for (int kk = 0; kk < KC; ++kk) {
            float4 wr0 = *(const float4*)&sWr[kk][c0];
            float4 wr1 = *(const float4*)&sWr[kk][c0 + 4];
            float4 wo0 = *(const float4*)&sWo[kk][c0];
            float4 wo1 = *(const float4*)&sWo[kk][c0 + 4];
#pragma unroll
            for (int i = 0; i < 4; ++i) {
                float a  = sA[ng * 4 + i][kk];
                float xv = sX[ng * 4 + i][kk];
                acc[i][0] = fmaf(a, wr0.x, fmaf(xv, wo0.x, acc[i][0]));
                acc[i][1] = fmaf(a, wr0.y, fmaf(xv, wo0.y, acc[i][1]));
                acc[i][2] = fmaf(a, wr0.z, fmaf(xv, wo0.z, acc[i][2]));
                acc[i][3] = fmaf(a, wr0.w, fmaf(xv, wo0.w, acc[i][3]));
                acc[i][4] = fmaf(a, wr1.x, fmaf(xv, wo1.x, acc[i][4]));
                acc[i][5] = fmaf(a, wr1.y, fmaf(xv, wo1.y, acc[i][5]));
                acc[i][6] = fmaf(a, wr1.z, fmaf(xv, wo1.z, acc[i][6]));
                acc[i][7] = fmaf(a, wr1.w, fmaf(xv, wo1.w, acc[i][7]));
            }
        }
    }

    const float4 bb0 = *(const float4*)(bias + c0);
    const float4 bb1 = *(const float4*)(bias + c0 + 4);
#pragma unroll
    for (int i = 0; i < 4; ++i) {
        int node = n0 + ng * 4 + i;
        if (node < N) {
            float4 o0, o1;
            o0.x = fmaxf(acc[i][0] + bb0.x, 0.f);
            o0.y = fmaxf(acc[i][1] + bb0.y, 0.f);
            o0.z = fmaxf(acc[i][2] + bb0.z, 0.f);
            o0.w = fmaxf(acc[i][3] + bb0.w, 0.f);
            o1.x = fmaxf(acc[i][4] + bb1.x, 0.f);
            o1.y = fmaxf(acc[i][5] + bb1.y, 0.f);
            o1.z = fmaxf(acc[i][6] + bb1.z, 0.f);
            o1.w = fmaxf(acc[i][7] + bb1.w, 0.f);
            *(float4*)(out + (size_t)node * HID_C + c0)     = o0;
            *(float4*)(out + (size_t)node * HID_C + c0 + 4) = o1;
        }
    }
}

// ---------------------------------------------------------------------------
// Mean-pool partials over sorted batch ids.
// ---------------------------------------------------------------------------
__global__ __launch_bounds__(128) void pool_kernel(
    const float* __restrict__ h, const int* __restrict__ batch,
    float* __restrict__ pooled, float* __restrict__ cnts, int N)
{
    int j  = threadIdx.x;
    int n0 = blockIdx.x * 128;
    int nend = min(n0 + 128, N);
    int cur = -1;
    float sum = 0.f, cnt = 0.f;
    for (int n = n0; n < nend; ++n) {
        int g = batch[n];
        if (g != cur) {
            if (cur >= 0) {
                atomicAdd(&pooled[cur * HID_C + j], sum);
                if (j == 0) atomicAdd(&cnts[cur], cnt);
            }
            cur = g; sum = 0.f; cnt = 0.f;
        }
        sum += h[(size_t)n * HID_C + j];
        cnt += 1.f;
    }
    if (cur >= 0) {
        atomicAdd(&pooled[cur * HID_C + j], sum);
        if (j == 0) atomicAdd(&cnts[cur], cnt);
    }
}

// ---------------------------------------------------------------------------
// Head: mean, fc1+relu, fc2, softmax. One block per graph.
// ---------------------------------------------------------------------------
__global__ __launch_bounds__(128) void head_kernel(
    const float* __restrict__ pooled, const float* __restrict__ cnts,
    const float* __restrict__ fc1w, const float* __restrict__ fc1b,
    const float* __restrict__ fc2w, const float* __restrict__ fc2b,
    float* __restrict__ out)
{
    __shared__ float sp[HID_C];
    __shared__ float so[HID_C];
    __shared__ float sl[64];
    __shared__ float sred[2];
    int g = blockIdx.x;
    int j = threadIdx.x;

    float inv = 1.f / fmaxf(cnts[g], 1.f);
    sp[j] = pooled[g * HID_C + j] * inv;
    __syncthreads();

    float a = fc1b[j];
    for (int k = 0; k < HID_C; ++k) a = fmaf(sp[k], fc1w[k * HID_C + j], a);
    so[j] = fmaxf(a, 0.f);
    __syncthreads();

    if (j < N_ASSETS_C) {
        float l = fc2b[j];
        for (int k = 0; k < HID_C; ++k) l = fmaf(so[k], fc2w[k * N_ASSETS_C + j], l);
        sl[j] = l;
    }
    __syncthreads();

    if (j == 0) {
        float m = -1e30f;
        for (int q = 0; q < N_ASSETS_C; ++q) m = fmaxf(m, sl[q]);
        sred[0] = m;
    }
    __syncthreads();
    if (j < N_ASSETS_C) sl[j] = expf(sl[j] - sred[0]);
    __syncthreads();
    if (j == 0) {
        float s = 0.f;
        for (int q = 0; q < N_ASSETS_C; ++q) s += sl[q];
        sred[1] = 1.f / s;
    }
    __syncthreads();
    if (j < N_ASSETS_C) out[g * N_ASSETS_C + j] = sl[j] * sred[1];
}

// ---------------------------------------------------------------------------
extern "C" void kernel_launch(void* const* d_in, const int* in_sizes, int n_in,
                              void* d_out, int out_size, void* d_ws, size_t ws_size,
                              hipStream_t stream)
{
    const float* x       = (const float*)d_in[0];
    const int*   ei      = (const int*)d_in[1];
    const int*   batch   = (const int*)d_in[2];
    const float* w1_rel  = (const float*)d_in[3];
    const float* b1      = (const float*)d_in[4];
    const float* w1_root = (const float*)d_in[5];
    const float* w2_rel  = (const float*)d_in[6];
    const float* b2      = (const float*)d_in[7];
    const float* w2_root = (const float*)d_in[8];
    const float* fc1w    = (const float*)d_in[9];
    const float* fc1b    = (const float*)d_in[10];
    const float* fc2w    = (const float*)d_in[11];
    const float* fc2b    = (const float*)d_in[12];
    float* out = (float*)d_out;

    char* ws = (char*)d_ws;
    // Workspace layout (peak live 153.7 MB; proven ws >= 179 MB in round 1):
    //   h2 region [0, 51,200,000) overlays (all dead before conv2 writes h2):
    //     tmp     @ 0           E u32  (6,400,000)
    //     col     @ 6,400,000   E int  (6,400,000)
    //     agg1    @ 12,800,000  N x 64 f32 (25,600,000)
    //     row_ptr @ 38,400,000  (N+1) int (400,004)
    //   h1      @ 51,200,000    N x 128 f32
    //   agg2    @ 102,400,000   N x 128 f32
    //   pooled  @ 153,600,000   64 x 128 f32 [zeroed]
    //   cnts    @ 153,632,768   64 f32       [zeroed]
    //   bcnt    @ 153,633,024   NB_BKT int   [zeroed]
    //   bbase   @ 153,633,824   NB_BKT+1 int
    //   gcur    @ 153,634,624   NB_BKT int
    unsigned* tmp     = (unsigned*)(ws + 0);
    int*      col     = (int*)(ws + 6400000);
    float*    agg1    = (float*)(ws + 12800000);
    int*      row_ptr = (int*)(ws + 38400000);
    float*    h2      = (float*)(ws + 0);
    float*    h1      = (float*)(ws + 51200000);
    float*    agg2    = (float*)(ws + 102400000);
    float*    pooled  = (float*)(ws + 153600000);
    float*    cnts    = (float*)(ws + 153632768);
    int*      bcnt    = (int*)(ws + 153633024);
    int*      bbase   = (int*)(ws + 153633824);
    int*      gcur    = (int*)(ws + 153634624);

    hipMemsetAsync(pooled, 0, 33024, stream);          // pooled + cnts
    hipMemsetAsync(bcnt, 0, NB_BKT * sizeof(int), stream);

    // ---- CSR build via bucketed counting sort ----
    bucket_hist_kernel<<<(N_EDGES_C + 2047) / 2048, 256, 0, stream>>>(ei, bcnt);
    bucket_scan_kernel<<<1, 256, 0, stream>>>(bcnt, bbase, gcur);
    partition_kernel<<<NBLK_A, 256, 0, stream>>>(ei, gcur, tmp);
    bucket_sort_kernel<<<NB_BKT, 256, 0, stream>>>(tmp, bbase, row_ptr, col);

    const int ggrid = (N_NODES_C + 3) / 4;       // 25000
    const int cgrid = (N_NODES_C + 63) / 64;     // 1563

    // ---- Layer 1 ----
    gather_kernel<IN_DIM_C><<<ggrid, 256, 0, stream>>>(x, row_ptr, col, agg1);
    conv_kernel<IN_DIM_C><<<cgrid, 256, 0, stream>>>(agg1, x, w1_rel, w1_root, b1, h1, N_NODES_C);

    // ---- Layer 2 ----
    gather_kernel<HID_C><<<ggrid, 256, 0, stream>>>(h1, row_ptr, col, agg2);
    conv_kernel<HID_C><<<cgrid, 256, 0, stream>>>(agg2, h1, w2_rel, w2_root, b2, h2, N_NODES_C);

    // ---- Pool + head ----
    const int pgrid = (N_NODES_C + 127) / 128;   // 782
    pool_kernel<<<pgrid, 128, 0, stream>>>(h2, batch, pooled, cnts, N_NODES_C);
    head_kernel<<<N_GRAPHS_C, 128, 0, stream>>>(pooled, cnts, fc1w, fc1b, fc2w, fc2b, out);
}

// Round 4
// 476.061 us; speedup vs baseline: 9.1205x; 1.2039x over previous
//
#include <hip/hip_runtime.h>
#include <math.h>

#define N_NODES_C 100000
#define N_EDGES_C 1600000
#define IN_DIM_C 64
#define HID_C 128
#define N_ASSETS_C 50
#define N_GRAPHS_C 64

#define BKT_SHIFT 9
#define BKT_NODES 512
#define NB_BKT ((N_NODES_C + BKT_NODES - 1) / BKT_NODES)   // 196
#define EPB_A 8192
#define NBLK_A ((N_EDGES_C + EPB_A - 1) / EPB_A)            // 196

typedef __attribute__((ext_vector_type(8))) short bf16x8;
typedef __attribute__((ext_vector_type(4))) float f32x4;

__device__ __forceinline__ unsigned short f2bf(float f) {
    unsigned u = __float_as_uint(f);
    return (unsigned short)((u + 0x7FFFu + ((u >> 16) & 1u)) >> 16);
}
__device__ __forceinline__ float bf2f(unsigned short b) {
    return __uint_as_float((unsigned)b << 16);
}

// ---------------------------------------------------------------------------
// fp32 -> bf16 cast (vectorized), n4 = count/4
// ---------------------------------------------------------------------------
__global__ __launch_bounds__(256) void cast_bf16_kernel(
    const float* __restrict__ src, unsigned short* __restrict__ dst, int n4)
{
    int i = blockIdx.x * 256 + threadIdx.x;
    if (i < n4) {
        float4 v = ((const float4*)src)[i];
        ushort4 o;
        o.x = f2bf(v.x); o.y = f2bf(v.y); o.z = f2bf(v.z); o.w = f2bf(v.w);
        ((ushort4*)dst)[i] = o;
    }
}

// ---------------------------------------------------------------------------
// Pack fp32 weight [Kw x 128] into MFMA B-fragments, split hi/lo bf16.
// Layout: [(kc*8+ct)*2 + {0=hi,1=lo}][lane][8].
// Grid: (Kw/32)*8 blocks of 64 threads.
// ---------------------------------------------------------------------------
__global__ __launch_bounds__(64) void pack_w_kernel(
    const float* __restrict__ W, unsigned short* __restrict__ dst)
{
    int kc = blockIdx.x >> 3;
    int ct = blockIdx.x & 7;
    int lane = threadIdx.x;
    int quad = lane >> 4;
    int l16 = lane & 15;
    unsigned short hi[8], lo[8];
#pragma unroll
    for (int j = 0; j < 8; ++j) {
        float w = W[(size_t)(kc * 32 + quad * 8 + j) * HID_C + ct * 16 + l16];
        unsigned short h = f2bf(w);
        float r = w - bf2f(h);
        hi[j] = h;
        lo[j] = f2bf(r);
    }
    size_t base = ((size_t)(kc * 8 + ct) * 2) * 512 + (size_t)lane * 8;
#pragma unroll
    for (int j = 0; j < 8; ++j) {
        dst[base + j] = hi[j];
        dst[base + 512 + j] = lo[j];
    }
}

// ---------------------------------------------------------------------------
// CSR build: bucketed counting sort (round-3 kernels, unchanged).
// ---------------------------------------------------------------------------
__global__ __launch_bounds__(256) void bucket_hist_kernel(
    const int* __restrict__ ei, int* __restrict__ bcnt)
{
    __shared__ int cnt[NB_BKT];
    int t = threadIdx.x;
    for (int i = t; i < NB_BKT; i += 256) cnt[i] = 0;
    __syncthreads();
    int base = blockIdx.x * 2048;
#pragma unroll
    for (int i = 0; i < 8; ++i) {
        int e = base + i * 256 + t;
        if (e < N_EDGES_C) {
            int dst = ei[N_EDGES_C + e];
            atomicAdd(&cnt[dst >> BKT_SHIFT], 1);
        }
    }
    __syncthreads();
    for (int i = t; i < NB_BKT; i += 256)
        if (cnt[i]) atomicAdd(&bcnt[i], cnt[i]);
}

__global__ __launch_bounds__(256) void bucket_scan_kernel(
    const int* __restrict__ bcnt, int* __restrict__ bbase, int* __restrict__ gcur)
{
    __shared__ int s[256];
    int t = threadIdx.x;
    int v = (t < NB_BKT) ? bcnt[t] : 0;
    s[t] = v;
    __syncthreads();
    for (int o = 1; o < 256; o <<= 1) {
        int x = (t >= o) ? s[t - o] : 0;
        __syncthreads();
        s[t] += x;
        __syncthreads();
    }
    int excl = s[t] - v;
    if (t < NB_BKT) { bbase[t] = excl; gcur[t] = excl; }
    if (t == 255) bbase[NB_BKT] = s[255];
}

__global__ __launch_bounds__(256) void partition_kernel(
    const int* __restrict__ ei, int* __restrict__ gcur,
    unsigned* __restrict__ tmp)
{
    __shared__ unsigned stage[EPB_A];
    __shared__ unsigned stage2[EPB_A];
    __shared__ unsigned char sbkt[EPB_A];
    __shared__ unsigned char sbkt2[EPB_A];
    __shared__ int cnt[NB_BKT];
    __shared__ int base[NB_BKT];
    __shared__ int cur[NB_BKT];
    __shared__ int gb[NB_BKT];
    __shared__ int s[256];

    const int t = threadIdx.x;
    const int e0 = blockIdx.x * EPB_A;
    const int nE = min(EPB_A, N_EDGES_C - e0);

    for (int i = t; i < NB_BKT; i += 256) cnt[i] = 0;
    __syncthreads();

    for (int idx = t; idx < nE; idx += 256) {
        int e = e0 + idx;
        int src = ei[e];
        int dst = ei[N_EDGES_C + e];
        int b = dst >> BKT_SHIFT;
        stage[idx] = ((unsigned)(dst & (BKT_NODES - 1)) << 17) | (unsigned)src;
        sbkt[idx] = (unsigned char)b;
        atomicAdd(&cnt[b], 1);
    }
    __syncthreads();

    int v = (t < NB_BKT) ? cnt[t] : 0;
    s[t] = v;
    __syncthreads();
    for (int o = 1; o < 256; o <<= 1) {
        int x = (t >= o) ? s[t - o] : 0;
        __syncthreads();
        s[t] += x;
        __syncthreads();
    }
    if (t < NB_BKT) {
        int excl = s[t] - v;
        base[t] = excl;
        cur[t] = excl;
        gb[t] = atomicAdd(&gcur[t], v);
    }
    __syncthreads();

    for (int idx = t; idx < nE; idx += 256) {
        int b = sbkt[idx];
        int p = atomicAdd(&cur[b], 1);
        stage2[p] = stage[idx];
        sbkt2[p] = (unsigned char)b;
    }
    __syncthreads();

    for (int idx = t; idx < nE; idx += 256) {
        int b = sbkt2[idx];
        int dest = gb[b] + (idx - base[b]);
        tmp[dest] = stage2[idx];
    }
}

__global__ __launch_bounds__(256) void bucket_sort_kernel(
    const unsigned* __restrict__ tmp, const int* __restrict__ bbase,
    int* __restrict__ row_ptr, int* __restrict__ col)
{
    __shared__ int ldeg[BKT_NODES];
    __shared__ int lsum[256];
    const int t = threadIdx.x;
    const int b = blockIdx.x;
    const int beg = bbase[b];
    const int end = bbase[b + 1];

    ldeg[t] = 0; ldeg[t + 256] = 0;
    __syncthreads();

    for (int p = beg + t; p < end; p += 256)
        atomicAdd(&ldeg[tmp[p] >> 17], 1);
    __syncthreads();

    int a0 = ldeg[2 * t], a1 = ldeg[2 * t + 1];
    int pair = a0 + a1;
    lsum[t] = pair;
    __syncthreads();
    for (int o = 1; o < 256; o <<= 1) {
        int x = (t >= o) ? lsum[t - o] : 0;
        __syncthreads();
        lsum[t] += x;
        __syncthreads();
    }
    int ep = lsum[t] - pair;
    __syncthreads();
    ldeg[2 * t] = ep;
    ldeg[2 * t + 1] = ep + a0;

    int gn0 = b * BKT_NODES + 2 * t;
    if (gn0 < N_NODES_C)     row_ptr[gn0] = beg + ep;
    if (gn0 + 1 < N_NODES_C) row_ptr[gn0 + 1] = beg + ep + a0;
    if (b == NB_BKT - 1 && t == 0) row_ptr[N_NODES_C] = N_EDGES_C;
    __syncthreads();

    for (int p = beg + t; p < end; p += 256) {
        unsigned v = tmp[p];
        int pos = atomicAdd(&ldeg[v >> 17], 1);
        col[beg + pos] = (int)(v & 0x1FFFFu);
    }
}

// ---------------------------------------------------------------------------
// bf16 gathers: agg[n] = sum feat[col[e]] ; fp32 accumulation, bf16 out.
// ---------------------------------------------------------------------------
__global__ __launch_bounds__(256) void gather_bf64_kernel(
    const unsigned short* __restrict__ feat, const int* __restrict__ row_ptr,
    const int* __restrict__ col, unsigned short* __restrict__ agg)
{
    int wave = threadIdx.x >> 6;
    int lane = threadIdx.x & 63;
    int n = blockIdx.x * 4 + wave;
    if (n >= N_NODES_C) return;
    int beg = row_ptr[n], end = row_ptr[n + 1];
    float s = 0.f;
    int e = beg;
    for (; e + 1 < end; e += 2) {
        int a = col[e], b = col[e + 1];
        s += bf2f(feat[(size_t)a * 64 + lane]) + bf2f(feat[(size_t)b * 64 + lane]);
    }
    if (e < end) s += bf2f(feat[(size_t)col[e] * 64 + lane]);
    agg[(size_t)n * 64 + lane] = f2bf(s);
}

__global__ __launch_bounds__(256) void gather_bf128_kernel(
    const unsigned short* __restrict__ feat, const int* __restrict__ row_ptr,
    const int* __restrict__ col, unsigned short* __restrict__ agg)
{
    int wave = threadIdx.x >> 6;
    int lane = threadIdx.x & 63;
    int n = blockIdx.x * 4 + wave;
    if (n >= N_NODES_C) return;
    int beg = row_ptr[n], end = row_ptr[n + 1];
    const unsigned* f = (const unsigned*)feat;
    float sx = 0.f, sy = 0.f;
    int e = beg;
    for (; e + 1 < end; e += 2) {
        int a = col[e], b = col[e + 1];
        unsigned ua = f[(size_t)a * 64 + lane];
        unsigned ub = f[(size_t)b * 64 + lane];
        sx += __uint_as_float(ua << 16) + __uint_as_float(ub << 16);
        sy += __uint_as_float(ua & 0xFFFF0000u) + __uint_as_float(ub & 0xFFFF0000u);
    }
    if (e < end) {
        unsigned u = f[(size_t)col[e] * 64 + lane];
        sx += __uint_as_float(u << 16);
        sy += __uint_as_float(u & 0xFFFF0000u);
    }
    ((unsigned*)agg)[(size_t)n * 64 + lane] =
        (unsigned)f2bf(sx) | ((unsigned)f2bf(sy) << 16);
}

// ---------------------------------------------------------------------------
// MFMA conv: out = relu([A|X] @ [Wr;Wo] + bias), bf16 in, fp32 acc.
// Weights packed hi/lo (split precision -> weight error ~2^-16).
// Block = 256 thr = 4 waves; tile 64 nodes x 128 cols; wave w -> cols w*32..
// ---------------------------------------------------------------------------
template<int K>
__device__ __forceinline__ void conv_phase(
    const unsigned short* __restrict__ P, const unsigned short* __restrict__ WP,
    const int* rowIdx, int quad, int lane, int wv, f32x4 acc[4][2])
{
#pragma unroll
    for (int kc = 0; kc < K / 32; ++kc) {
        bf16x8 afr[4];
#pragma unroll
        for (int rt = 0; rt < 4; ++rt)
            afr[rt] = *(const bf16x8*)(P + (size_t)rowIdx[rt] * K + kc * 32 + quad * 8);
#pragma unroll
        for (int ci = 0; ci < 2; ++ci) {
            int ct = wv * 2 + ci;
            const unsigned short* bp = WP + ((size_t)(kc * 8 + ct) * 2) * 512 + (size_t)lane * 8;
            bf16x8 bhi = *(const bf16x8*)bp;
            bf16x8 blo = *(const bf16x8*)(bp + 512);
#pragma unroll
            for (int rt = 0; rt < 4; ++rt) {
                acc[rt][ci] = __builtin_amdgcn_mfma_f32_16x16x32_bf16(afr[rt], bhi, acc[rt][ci], 0, 0, 0);
                acc[rt][ci] = __builtin_amdgcn_mfma_f32_16x16x32_bf16(afr[rt], blo, acc[rt][ci], 0, 0, 0);
            }
        }
    }
}

template<int KA, int KX, bool OUTF32>
__global__ __launch_bounds__(256) void conv_mfma_kernel(
    const unsigned short* __restrict__ A, const unsigned short* __restrict__ X,
    const unsigned short* __restrict__ WrP, const unsigned short* __restrict__ WoP,
    const float* __restrict__ bias, void* __restrict__ outp, int N)
{
    const int t = threadIdx.x;
    const int wv = t >> 6;
    const int lane = t & 63;
    const int quad = lane >> 4;
    const int l16 = lane & 15;
    const int n0 = blockIdx.x * 64;

    f32x4 acc[4][2];
#pragma unroll
    for (int rt = 0; rt < 4; ++rt)
#pragma unroll
        for (int ci = 0; ci < 2; ++ci)
            acc[rt][ci] = (f32x4){0.f, 0.f, 0.f, 0.f};

    int rowIdx[4];
#pragma unroll
    for (int rt = 0; rt < 4; ++rt) {
        int r = n0 + rt * 16 + l16;
        rowIdx[rt] = (r < N) ? r : (N - 1);
    }

    conv_phase<KA>(A, WrP, rowIdx, quad, lane, wv, acc);
    conv_phase<KX>(X, WoP, rowIdx, quad, lane, wv, acc);

#pragma unroll
    for (int ci = 0; ci < 2; ++ci) {
        int colg = wv * 32 + ci * 16 + l16;
        float bv = bias[colg];
#pragma unroll
        for (int rt = 0; rt < 4; ++rt) {
            int nbase = n0 + rt * 16 + quad * 4;
#pragma unroll
            for (int r = 0; r < 4; ++r) {
                int node = nbase + r;
                if (node < N) {
                    float v = fmaxf(acc[rt][ci][r] + bv, 0.f);
                    if (OUTF32)
                        ((float*)outp)[(size_t)node * HID_C + colg] = v;
                    else
                        ((unsigned short*)outp)[(size_t)node * HID_C + colg] = f2bf(v);
                }
            }
        }
    }
}

// ---------------------------------------------------------------------------
// Mean-pool partials over sorted batch ids (h2 fp32).
// ---------------------------------------------------------------------------
__global__ __launch_bounds__(128) void pool_kernel(
    const float* __restrict__ h, const int* __restrict__ batch,
    float* __restrict__ pooled, float* __restrict__ cnts, int N)
{
    int j  = threadIdx.x;
    int n0 = blockIdx.x * 128;
    int nend = min(n0 + 128, N);
    int cur = -1;
    float sum = 0.f, cnt = 0.f;
    for (int n = n0; n < nend; ++n) {
        int g = batch[n];
        if (g != cur) {
            if (cur >= 0) {
                atomicAdd(&pooled[cur * HID_C + j], sum);
                if (j == 0) atomicAdd(&cnts[cur], cnt);
            }
            cur = g; sum = 0.f; cnt = 0.f;
        }
        sum += h[(size_t)n * HID_C + j];
        cnt += 1.f;
    }
    if (cur >= 0) {
        atomicAdd(&pooled[cur * HID_C + j], sum);
        if (j == 0) atomicAdd(&cnts[cur], cnt);
    }
}

// ---------------------------------------------------------------------------
// Head: mean, fc1+relu, fc2, softmax (all fp32). One block per graph.
// ---------------------------------------------------------------------------
__global__ __launch_bounds__(128) void head_kernel(
    const float* __restrict__ pooled, const float* __restrict__ cnts,
    const float* __restrict__ fc1w, const float* __restrict__ fc1b,
    const float* __restrict__ fc2w, const float* __restrict__ fc2b,
    float* __restrict__ out)
{
    __shared__ float sp[HID_C];
    __shared__ float so[HID_C];
    __shared__ float sl[64];
    __shared__ float sred[2];
    int g = blockIdx.x;
    int j = threadIdx.x;

    float inv = 1.f / fmaxf(cnts[g], 1.f);
    sp[j] = pooled[g * HID_C + j] * inv;
    __syncthreads();

    float a = fc1b[j];
    for (int k = 0; k < HID_C; ++k) a = fmaf(sp[k], fc1w[k * HID_C + j], a);
    so[j] = fmaxf(a, 0.f);
    __syncthreads();

    if (j < N_ASSETS_C) {
        float l = fc2b[j];
        for (int k = 0; k < HID_C; ++k) l = fmaf(so[k], fc2w[k * N_ASSETS_C + j], l);
        sl[j] = l;
    }
    __syncthreads();

    if (j == 0) {
        float m = -1e30f;
        for (int q = 0; q < N_ASSETS_C; ++q) m = fmaxf(m, sl[q]);
        sred[0] = m;
    }
    __syncthreads();
    if (j < N_ASSETS_C) sl[j] = expf(sl[j] - sred[0]);
    __syncthreads();
    if (j == 0) {
        float s = 0.f;
        for (int q = 0; q < N_ASSETS_C; ++q) s += sl[q];
        sred[1] = 1.f / s;
    }
    __syncthreads();
    if (j < N_ASSETS_C) out[g * N_ASSETS_C + j] = sl[j] * sred[1];
}

// ---------------------------------------------------------------------------
extern "C" void kernel_launch(void* const* d_in, const int* in_sizes, int n_in,
                              void* d_out, int out_size, void* d_ws, size_t ws_size,
                              hipStream_t stream)
{
    const float* x       = (const float*)d_in[0];
    const int*   ei      = (const int*)d_in[1];
    const int*   batch   = (const int*)d_in[2];
    const float* w1_rel  = (const float*)d_in[3];
    const float* b1      = (const float*)d_in[4];
    const float* w1_root = (const float*)d_in[5];
    const float* w2_rel  = (const float*)d_in[6];
    const float* b2      = (const float*)d_in[7];
    const float* w2_root = (const float*)d_in[8];
    const float* fc1w    = (const float*)d_in[9];
    const float* fc1b    = (const float*)d_in[10];
    const float* fc2w    = (const float*)d_in[11];
    const float* fc2b    = (const float*)d_in[12];
    float* out = (float*)d_out;

    char* ws = (char*)d_ws;
    // Flat workspace layout (no aliasing), total 141.5 MB:
    unsigned*       tmp     = (unsigned*)(ws + 0);              //  6,400,000
    int*            col     = (int*)(ws + 6400000);             //  6,400,000
    int*            row_ptr = (int*)(ws + 12800000);            //    400,016
    int*            bcnt    = (int*)(ws + 13200016);            //        800
    int*            bbase   = (int*)(ws + 13200816);            //        800
    int*            gcur    = (int*)(ws + 13201616);            //        800
    unsigned short* wp1r    = (unsigned short*)(ws + 13202432); //     32,768
    unsigned short* wp1o    = (unsigned short*)(ws + 13235200); //     32,768
    unsigned short* wp2r    = (unsigned short*)(ws + 13267968); //     65,536
    unsigned short* wp2o    = (unsigned short*)(ws + 13333504); //     65,536
    float*          pooled  = (float*)(ws + 13399040);          //     32,768
    float*          cnts    = (float*)(ws + 13431808);          //        256
    unsigned short* xb      = (unsigned short*)(ws + 13432064); // 12,800,000
    unsigned short* agg1b   = (unsigned short*)(ws + 26232064); // 12,800,000
    unsigned short* h1b     = (unsigned short*)(ws + 39032064); // 25,600,000
    unsigned short* agg2b   = (unsigned short*)(ws + 64632064); // 25,600,000
    float*          h2      = (float*)(ws + 90232064);          // 51,200,000

    hipMemsetAsync(pooled, 0, 33024, stream);   // pooled + cnts
    hipMemsetAsync(bcnt, 0, 800, stream);

    // ---- casts & weight packing ----
    cast_bf16_kernel<<<(N_NODES_C * IN_DIM_C / 4 + 255) / 256, 256, 0, stream>>>(x, xb, N_NODES_C * IN_DIM_C / 4);
    pack_w_kernel<<<(IN_DIM_C / 32) * 8, 64, 0, stream>>>(w1_rel,  wp1r);
    pack_w_kernel<<<(IN_DIM_C / 32) * 8, 64, 0, stream>>>(w1_root, wp1o);
    pack_w_kernel<<<(HID_C  / 32) * 8, 64, 0, stream>>>(w2_rel,  wp2r);
    pack_w_kernel<<<(HID_C  / 32) * 8, 64, 0, stream>>>(w2_root, wp2o);

    // ---- CSR build (bucketed counting sort) ----
    bucket_hist_kernel<<<(N_EDGES_C + 2047) / 2048, 256, 0, stream>>>(ei, bcnt);
    bucket_scan_kernel<<<1, 256, 0, stream>>>(bcnt, bbase, gcur);
    partition_kernel<<<NBLK_A, 256, 0, stream>>>(ei, gcur, tmp);
    bucket_sort_kernel<<<NB_BKT, 256, 0, stream>>>(tmp, bbase, row_ptr, col);

    const int ggrid = (N_NODES_C + 3) / 4;       // 25000
    const int cgrid = (N_NODES_C + 63) / 64;     // 1563

    // ---- Layer 1 ----
    gather_bf64_kernel<<<ggrid, 256, 0, stream>>>(xb, row_ptr, col, agg1b);
    conv_mfma_kernel<IN_DIM_C, IN_DIM_C, false><<<cgrid, 256, 0, stream>>>(
        agg1b, xb, wp1r, wp1o, b1, (void*)h1b, N_NODES_C);

    // ---- Layer 2 ----
    gather_bf128_kernel<<<ggrid, 256, 0, stream>>>(h1b, row_ptr, col, agg2b);
    conv_mfma_kernel<HID_C, HID_C, true><<<cgrid, 256, 0, stream>>>(
        agg2b, h1b, wp2r, wp2o, b2, (void*)h2, N_NODES_C);

    // ---- Pool + head ----
    const int pgrid = (N_NODES_C + 127) / 128;   // 782
    pool_kernel<<<pgrid, 128, 0, stream>>>(h2, batch, pooled, cnts, N_NODES_C);
    head_kernel<<<N_GRAPHS_C, 128, 0, stream>>>(pooled, cnts, fc1w, fc1b, fc2w, fc2b, out);
}

// Round 5
// 394.926 us; speedup vs baseline: 10.9942x; 1.2054x over previous
//
#include <hip/hip_runtime.h>
#include <math.h>

#define N_NODES_C 100000
#define N_EDGES_C 1600000
#define IN_DIM_C 64
#define HID_C 128
#define N_ASSETS_C 50
#define N_GRAPHS_C 64

#define BKT_SHIFT 9
#define BKT_NODES 512
#define NB_BKT ((N_NODES_C + BKT_NODES - 1) / BKT_NODES)   // 196
#define EPB_A 8192
#define NBLK_A ((N_EDGES_C + EPB_A - 1) / EPB_A)            // 196

typedef __attribute__((ext_vector_type(8))) short bf16x8;
typedef __attribute__((ext_vector_type(4))) float f32x4;

__device__ __forceinline__ unsigned short f2bf(float f) {
    unsigned u = __float_as_uint(f);
    return (unsigned short)((u + 0x7FFFu + ((u >> 16) & 1u)) >> 16);
}
__device__ __forceinline__ float bf2f(unsigned short b) {
    return __uint_as_float((unsigned)b << 16);
}

// ---------------------------------------------------------------------------
// fp32 -> bf16 cast (vectorized), n4 = count/4
// ---------------------------------------------------------------------------
__global__ __launch_bounds__(256) void cast_bf16_kernel(
    const float* __restrict__ src, unsigned short* __restrict__ dst, int n4)
{
    int i = blockIdx.x * 256 + threadIdx.x;
    if (i < n4) {
        float4 v = ((const float4*)src)[i];
        ushort4 o;
        o.x = f2bf(v.x); o.y = f2bf(v.y); o.z = f2bf(v.z); o.w = f2bf(v.w);
        ((ushort4*)dst)[i] = o;
    }
}

// ---------------------------------------------------------------------------
// Pack fp32 weight [Kw x 128] into MFMA B-fragments, split hi/lo bf16.
// Layout: [(kc*8+ct)*2 + {0=hi,1=lo}][lane][8].
// ---------------------------------------------------------------------------
__global__ __launch_bounds__(64) void pack_w_kernel(
    const float* __restrict__ W, unsigned short* __restrict__ dst)
{
    int kc = blockIdx.x >> 3;
    int ct = blockIdx.x & 7;
    int lane = threadIdx.x;
    int quad = lane >> 4;
    int l16 = lane & 15;
    unsigned short hi[8], lo[8];
#pragma unroll
    for (int j = 0; j < 8; ++j) {
        float w = W[(size_t)(kc * 32 + quad * 8 + j) * HID_C + ct * 16 + l16];
        unsigned short h = f2bf(w);
        float r = w - bf2f(h);
        hi[j] = h;
        lo[j] = f2bf(r);
    }
    size_t base = ((size_t)(kc * 8 + ct) * 2) * 512 + (size_t)lane * 8;
#pragma unroll
    for (int j = 0; j < 8; ++j) {
        dst[base + j] = hi[j];
        dst[base + 512 + j] = lo[j];
    }
}

// ---------------------------------------------------------------------------
// CSR build: bucketed counting sort.
// ---------------------------------------------------------------------------
__global__ __launch_bounds__(256) void bucket_hist_kernel(
    const int* __restrict__ ei, int* __restrict__ bcnt)
{
    __shared__ int cnt[NB_BKT];
    int t = threadIdx.x;
    for (int i = t; i < NB_BKT; i += 256) cnt[i] = 0;
    __syncthreads();
    int base = blockIdx.x * 2048;
#pragma unroll
    for (int i = 0; i < 8; ++i) {
        int e = base + i * 256 + t;
        if (e < N_EDGES_C) {
            int dst = ei[N_EDGES_C + e];
            atomicAdd(&cnt[dst >> BKT_SHIFT], 1);
        }
    }
    __syncthreads();
    for (int i = t; i < NB_BKT; i += 256)
        if (cnt[i]) atomicAdd(&bcnt[i], cnt[i]);
}

__global__ __launch_bounds__(256) void bucket_scan_kernel(
    const int* __restrict__ bcnt, int* __restrict__ bbase, int* __restrict__ gcur)
{
    __shared__ int s[256];
    int t = threadIdx.x;
    int v = (t < NB_BKT) ? bcnt[t] : 0;
    s[t] = v;
    __syncthreads();
    for (int o = 1; o < 256; o <<= 1) {
        int x = (t >= o) ? s[t - o] : 0;
        __syncthreads();
        s[t] += x;
        __syncthreads();
    }
    int excl = s[t] - v;
    if (t < NB_BKT) { bbase[t] = excl; gcur[t] = excl; }
    if (t == 255) bbase[NB_BKT] = s[255];
}

__global__ __launch_bounds__(256) void partition_kernel(
    const int* __restrict__ ei, int* __restrict__ gcur,
    unsigned* __restrict__ tmp)
{
    __shared__ unsigned stage[EPB_A];
    __shared__ unsigned stage2[EPB_A];
    __shared__ unsigned char sbkt[EPB_A];
    __shared__ unsigned char sbkt2[EPB_A];
    __shared__ int cnt[NB_BKT];
    __shared__ int base[NB_BKT];
    __shared__ int cur[NB_BKT];
    __shared__ int gb[NB_BKT];
    __shared__ int s[256];

    const int t = threadIdx.x;
    const int e0 = blockIdx.x * EPB_A;
    const int nE = min(EPB_A, N_EDGES_C - e0);

    for (int i = t; i < NB_BKT; i += 256) cnt[i] = 0;
    __syncthreads();

    for (int idx = t; idx < nE; idx += 256) {
        int e = e0 + idx;
        int src = ei[e];
        int dst = ei[N_EDGES_C + e];
        int b = dst >> BKT_SHIFT;
        stage[idx] = ((unsigned)(dst & (BKT_NODES - 1)) << 17) | (unsigned)src;
        sbkt[idx] = (unsigned char)b;
        atomicAdd(&cnt[b], 1);
    }
    __syncthreads();

    int v = (t < NB_BKT) ? cnt[t] : 0;
    s[t] = v;
    __syncthreads();
    for (int o = 1; o < 256; o <<= 1) {
        int x = (t >= o) ? s[t - o] : 0;
        __syncthreads();
        s[t] += x;
        __syncthreads();
    }
    if (t < NB_BKT) {
        int excl = s[t] - v;
        base[t] = excl;
        cur[t] = excl;
        gb[t] = atomicAdd(&gcur[t], v);
    }
    __syncthreads();

    for (int idx = t; idx < nE; idx += 256) {
        int b = sbkt[idx];
        int p = atomicAdd(&cur[b], 1);
        stage2[p] = stage[idx];
        sbkt2[p] = (unsigned char)b;
    }
    __syncthreads();

    for (int idx = t; idx < nE; idx += 256) {
        int b = sbkt2[idx];
        int dest = gb[b] + (idx - base[b]);
        tmp[dest] = stage2[idx];
    }
}

__global__ __launch_bounds__(256) void bucket_sort_kernel(
    const unsigned* __restrict__ tmp, const int* __restrict__ bbase,
    int* __restrict__ row_ptr, int* __restrict__ col)
{
    __shared__ int ldeg[BKT_NODES];
    __shared__ int lsum[256];
    const int t = threadIdx.x;
    const int b = blockIdx.x;
    const int beg = bbase[b];
    const int end = bbase[b + 1];

    ldeg[t] = 0; ldeg[t + 256] = 0;
    __syncthreads();

    for (int p = beg + t; p < end; p += 256)
        atomicAdd(&ldeg[tmp[p] >> 17], 1);
    __syncthreads();

    int a0 = ldeg[2 * t], a1 = ldeg[2 * t + 1];
    int pair = a0 + a1;
    lsum[t] = pair;
    __syncthreads();
    for (int o = 1; o < 256; o <<= 1) {
        int x = (t >= o) ? lsum[t - o] : 0;
        __syncthreads();
        lsum[t] += x;
        __syncthreads();
    }
    int ep = lsum[t] - pair;
    __syncthreads();
    ldeg[2 * t] = ep;
    ldeg[2 * t + 1] = ep + a0;

    int gn0 = b * BKT_NODES + 2 * t;
    if (gn0 < N_NODES_C)     row_ptr[gn0] = beg + ep;
    if (gn0 + 1 < N_NODES_C) row_ptr[gn0 + 1] = beg + ep + a0;
    if (b == NB_BKT - 1 && t == 0) row_ptr[N_NODES_C] = N_EDGES_C;
    __syncthreads();

    for (int p = beg + t; p < end; p += 256) {
        unsigned v = tmp[p];
        int pos = atomicAdd(&ldeg[v >> 17], 1);
        col[beg + pos] = (int)(v & 0x1FFFFu);
    }
}

// ---------------------------------------------------------------------------
// Multi-edge gathers: 16-lane (W=128) / 8-lane (W=64) groups, dwordx4 loads,
// 4 (resp. 8) edges in flight per VMEM instr, shfl_xor cross-group reduce.
// ---------------------------------------------------------------------------
__global__ __launch_bounds__(256) void gather_bf128_kernel(
    const unsigned short* __restrict__ feat, const int* __restrict__ row_ptr,
    const int* __restrict__ col, unsigned short* __restrict__ agg)
{
    int wave = threadIdx.x >> 6;
    int lane = threadIdx.x & 63;
    int g = lane >> 4;     // edge subgroup 0..3
    int c = lane & 15;     // 16B chunk within row (row = 16 x uint4)
    int n = blockIdx.x * 4 + wave;
    if (n >= N_NODES_C) return;
    int beg = row_ptr[n], end = row_ptr[n + 1];
    const uint4* f4 = (const uint4*)feat;

    float acc[8];
#pragma unroll
    for (int j = 0; j < 8; ++j) acc[j] = 0.f;

    int e = beg + g;
    for (; e + 4 < end; e += 8) {
        int s0 = col[e], s1 = col[e + 4];
        uint4 v0 = f4[(size_t)s0 * 16 + c];
        uint4 v1 = f4[(size_t)s1 * 16 + c];
        acc[0] += __uint_as_float(v0.x << 16) + __uint_as_float(v1.x << 16);
        acc[1] += __uint_as_float(v0.x & 0xFFFF0000u) + __uint_as_float(v1.x & 0xFFFF0000u);
        acc[2] += __uint_as_float(v0.y << 16) + __uint_as_float(v1.y << 16);
        acc[3] += __uint_as_float(v0.y & 0xFFFF0000u) + __uint_as_float(v1.y & 0xFFFF0000u);
        acc[4] += __uint_as_float(v0.z << 16) + __uint_as_float(v1.z << 16);
        acc[5] += __uint_as_float(v0.z & 0xFFFF0000u) + __uint_as_float(v1.z & 0xFFFF0000u);
        acc[6] += __uint_as_float(v0.w << 16) + __uint_as_float(v1.w << 16);
        acc[7] += __uint_as_float(v0.w & 0xFFFF0000u) + __uint_as_float(v1.w & 0xFFFF0000u);
    }
    if (e < end) {
        uint4 v = f4[(size_t)col[e] * 16 + c];
        acc[0] += __uint_as_float(v.x << 16);
        acc[1] += __uint_as_float(v.x & 0xFFFF0000u);
        acc[2] += __uint_as_float(v.y << 16);
        acc[3] += __uint_as_float(v.y & 0xFFFF0000u);
        acc[4] += __uint_as_float(v.z << 16);
        acc[5] += __uint_as_float(v.z & 0xFFFF0000u);
        acc[6] += __uint_as_float(v.w << 16);
        acc[7] += __uint_as_float(v.w & 0xFFFF0000u);
    }
#pragma unroll
    for (int j = 0; j < 8; ++j) {
        acc[j] += __shfl_xor(acc[j], 16, 64);
        acc[j] += __shfl_xor(acc[j], 32, 64);
    }
    if (g == 0) {
        uint4 o;
        o.x = (unsigned)f2bf(acc[0]) | ((unsigned)f2bf(acc[1]) << 16);
        o.y = (unsigned)f2bf(acc[2]) | ((unsigned)f2bf(acc[3]) << 16);
        o.z = (unsigned)f2bf(acc[4]) | ((unsigned)f2bf(acc[5]) << 16);
        o.w = (unsigned)f2bf(acc[6]) | ((unsigned)f2bf(acc[7]) << 16);
        ((uint4*)agg)[(size_t)n * 16 + c] = o;
    }
}

__global__ __launch_bounds__(256) void gather_bf64_kernel(
    const unsigned short* __restrict__ feat, const int* __restrict__ row_ptr,
    const int* __restrict__ col, unsigned short* __restrict__ agg)
{
    int wave = threadIdx.x >> 6;
    int lane = threadIdx.x & 63;
    int g = lane >> 3;     // edge subgroup 0..7
    int c = lane & 7;      // 16B chunk within row (row = 8 x uint4)
    int n = blockIdx.x * 4 + wave;
    if (n >= N_NODES_C) return;
    int beg = row_ptr[n], end = row_ptr[n + 1];
    const uint4* f4 = (const uint4*)feat;

    float acc[8];
#pragma unroll
    for (int j = 0; j < 8; ++j) acc[j] = 0.f;

    int e = beg + g;
    for (; e + 8 < end; e += 16) {
        int s0 = col[e], s1 = col[e + 8];
        uint4 v0 = f4[(size_t)s0 * 8 + c];
        uint4 v1 = f4[(size_t)s1 * 8 + c];
        acc[0] += __uint_as_float(v0.x << 16) + __uint_as_float(v1.x << 16);
        acc[1] += __uint_as_float(v0.x & 0xFFFF0000u) + __uint_as_float(v1.x & 0xFFFF0000u);
        acc[2] += __uint_as_float(v0.y << 16) + __uint_as_float(v1.y << 16);
        acc[3] += __uint_as_float(v0.y & 0xFFFF0000u) + __uint_as_float(v1.y & 0xFFFF0000u);
        acc[4] += __uint_as_float(v0.z << 16) + __uint_as_float(v1.z << 16);
        acc[5] += __uint_as_float(v0.z & 0xFFFF0000u) + __uint_as_float(v1.z & 0xFFFF0000u);
        acc[6] += __uint_as_float(v0.w << 16) + __uint_as_float(v1.w << 16);
        acc[7] += __uint_as_float(v0.w & 0xFFFF0000u) + __uint_as_float(v1.w & 0xFFFF0000u);
    }
    if (e < end) {
        uint4 v = f4[(size_t)col[e] * 8 + c];
        acc[0] += __uint_as_float(v.x << 16);
        acc[1] += __uint_as_float(v.x & 0xFFFF0000u);
        acc[2] += __uint_as_float(v.y << 16);
        acc[3] += __uint_as_float(v.y & 0xFFFF0000u);
        acc[4] += __uint_as_float(v.z << 16);
        acc[5] += __uint_as_float(v.z & 0xFFFF0000u);
        acc[6] += __uint_as_float(v.w << 16);
        acc[7] += __uint_as_float(v.w & 0xFFFF0000u);
    }
#pragma unroll
    for (int j = 0; j < 8; ++j) {
        acc[j] += __shfl_xor(acc[j], 8, 64);
        acc[j] += __shfl_xor(acc[j], 16, 64);
        acc[j] += __shfl_xor(acc[j], 32, 64);
    }
    if (g == 0) {
        uint4 o;
        o.x = (unsigned)f2bf(acc[0]) | ((unsigned)f2bf(acc[1]) << 16);
        o.y = (unsigned)f2bf(acc[2]) | ((unsigned)f2bf(acc[3]) << 16);
        o.z = (unsigned)f2bf(acc[4]) | ((unsigned)f2bf(acc[5]) << 16);
        o.w = (unsigned)f2bf(acc[6]) | ((unsigned)f2bf(acc[7]) << 16);
        ((uint4*)agg)[(size_t)n * 8 + c] = o;
    }
}

// ---------------------------------------------------------------------------
// MFMA conv: out = relu([A|X] @ [Wr;Wo] + bias), bf16 in, fp32 acc.
// ---------------------------------------------------------------------------
template<int K>
__device__ __forceinline__ void conv_phase(
    const unsigned short* __restrict__ P, const unsigned short* __restrict__ WP,
    const int* rowIdx, int quad, int lane, int wv, f32x4 acc[4][2])
{
#pragma unroll
    for (int kc = 0; kc < K / 32; ++kc) {
        bf16x8 afr[4];
#pragma unroll
        for (int rt = 0; rt < 4; ++rt)
            afr[rt] = *(const bf16x8*)(P + (size_t)rowIdx[rt] * K + kc * 32 + quad * 8);
#pragma unroll
        for (int ci = 0; ci < 2; ++ci) {
            int ct = wv * 2 + ci;
            const unsigned short* bp = WP + ((size_t)(kc * 8 + ct) * 2) * 512 + (size_t)lane * 8;
            bf16x8 bhi = *(const bf16x8*)bp;
            bf16x8 blo = *(const bf16x8*)(bp + 512);
#pragma unroll
            for (int rt = 0; rt < 4; ++rt) {
                acc[rt][ci] = __builtin_amdgcn_mfma_f32_16x16x32_bf16(afr[rt], bhi, acc[rt][ci], 0, 0, 0);
                acc[rt][ci] = __builtin_amdgcn_mfma_f32_16x16x32_bf16(afr[rt], blo, acc[rt][ci], 0, 0, 0);
            }
        }
    }
}

template<int KA, int KX, bool OUTF32>
__global__ __launch_bounds__(256) void conv_mfma_kernel(
    const unsigned short* __restrict__ A, const unsigned short* __restrict__ X,
    const unsigned short* __restrict__ WrP, const unsigned short* __restrict__ WoP,
    const float* __restrict__ bias, void* __restrict__ outp, int N)
{
    const int t = threadIdx.x;
    const int wv = t >> 6;
    const int lane = t & 63;
    const int quad = lane >> 4;
    const int l16 = lane & 15;
    const int n0 = blockIdx.x * 64;

    f32x4 acc[4][2];
#pragma unroll
    for (int rt = 0; rt < 4; ++rt)
#pragma unroll
        for (int ci = 0; ci < 2; ++ci)
            acc[rt][ci] = (f32x4){0.f, 0.f, 0.f, 0.f};

    int rowIdx[4];
#pragma unroll
    for (int rt = 0; rt < 4; ++rt) {
        int r = n0 + rt * 16 + l16;
        rowIdx[rt] = (r < N) ? r : (N - 1);
    }

    conv_phase<KA>(A, WrP, rowIdx, quad, lane, wv, acc);
    conv_phase<KX>(X, WoP, rowIdx, quad, lane, wv, acc);

#pragma unroll
    for (int ci = 0; ci < 2; ++ci) {
        int colg = wv * 32 + ci * 16 + l16;
        float bv = bias[colg];
#pragma unroll
        for (int rt = 0; rt < 4; ++rt) {
            int nbase = n0 + rt * 16 + quad * 4;
#pragma unroll
            for (int r = 0; r < 4; ++r) {
                int node = nbase + r;
                if (node < N) {
                    float v = fmaxf(acc[rt][ci][r] + bv, 0.f);
                    if (OUTF32)
                        ((float*)outp)[(size_t)node * HID_C + colg] = v;
                    else
                        ((unsigned short*)outp)[(size_t)node * HID_C + colg] = f2bf(v);
                }
            }
        }
    }
}

// ---------------------------------------------------------------------------
// Mean-pool partials over sorted batch ids (h2 fp32).
// ---------------------------------------------------------------------------
__global__ __launch_bounds__(128) void pool_kernel(
    const float* __restrict__ h, const int* __restrict__ batch,
    float* __restrict__ pooled, float* __restrict__ cnts, int N)
{
    int j  = threadIdx.x;
    int n0 = blockIdx.x * 128;
    int nend = min(n0 + 128, N);
    int cur = -1;
    float sum = 0.f, cnt = 0.f;
    for (int n = n0; n < nend; ++n) {
        int g = batch[n];
        if (g != cur) {
            if (cur >= 0) {
                atomicAdd(&pooled[cur * HID_C + j], sum);
                if (j == 0) atomicAdd(&cnts[cur], cnt);
            }
            cur = g; sum = 0.f; cnt = 0.f;
        }
        sum += h[(size_t)n * HID_C + j];
        cnt += 1.f;
    }
    if (cur >= 0) {
        atomicAdd(&pooled[cur * HID_C + j], sum);
        if (j == 0) atomicAdd(&cnts[cur], cnt);
    }
}

// ---------------------------------------------------------------------------
// Head: mean, fc1+relu, fc2, softmax (all fp32). One block per graph.
// ---------------------------------------------------------------------------
__global__ __launch_bounds__(128) void head_kernel(
    const float* __restrict__ pooled, const float* __restrict__ cnts,
    const float* __restrict__ fc1w, const float* __restrict__ fc1b,
    const float* __restrict__ fc2w, const float* __restrict__ fc2b,
    float* __restrict__ out)
{
    __shared__ float sp[HID_C];
    __shared__ float so[HID_C];
    __shared__ float sl[64];
    __shared__ float sred[2];
    int g = blockIdx.x;
    int j = threadIdx.x;

    float inv = 1.f / fmaxf(cnts[g], 1.f);
    sp[j] = pooled[g * HID_C + j] * inv;
    __syncthreads();

    float a = fc1b[j];
    for (int k = 0; k < HID_C; ++k) a = fmaf(sp[k], fc1w[k * HID_C + j], a);
    so[j] = fmaxf(a, 0.f);
    __syncthreads();

    if (j < N_ASSETS_C) {
        float l = fc2b[j];
        for (int k = 0; k < HID_C; ++k) l = fmaf(so[k], fc2w[k * N_ASSETS_C + j], l);
        sl[j] = l;
    }
    __syncthreads();

    if (j == 0) {
        float m = -1e30f;
        for (int q = 0; q < N_ASSETS_C; ++q) m = fmaxf(m, sl[q]);
        sred[0] = m;
    }
    __syncthreads();
    if (j < N_ASSETS_C) sl[j] = expf(sl[j] - sred[0]);
    __syncthreads();
    if (j == 0) {
        float s = 0.f;
        for (int q = 0; q < N_ASSETS_C; ++q) s += sl[q];
        sred[1] = 1.f / s;
    }
    __syncthreads();
    if (j < N_ASSETS_C) out[g * N_ASSETS_C + j] = sl[j] * sred[1];
}

// ---------------------------------------------------------------------------
extern "C" void kernel_launch(void* const* d_in, const int* in_sizes, int n_in,
                              void* d_out, int out_size, void* d_ws, size_t ws_size,
                              hipStream_t stream)
{
    const float* x       = (const float*)d_in[0];
    const int*   ei      = (const int*)d_in[1];
    const int*   batch   = (const int*)d_in[2];
    const float* w1_rel  = (const float*)d_in[3];
    const float* b1      = (const float*)d_in[4];
    const float* w1_root = (const float*)d_in[5];
    const float* w2_rel  = (const float*)d_in[6];
    const float* b2      = (const float*)d_in[7];
    const float* w2_root = (const float*)d_in[8];
    const float* fc1w    = (const float*)d_in[9];
    const float* fc1b    = (const float*)d_in[10];
    const float* fc2w    = (const float*)d_in[11];
    const float* fc2b    = (const float*)d_in[12];
    float* out = (float*)d_out;

    char* ws = (char*)d_ws;
    unsigned*       tmp     = (unsigned*)(ws + 0);              //  6,400,000
    int*            col     = (int*)(ws + 6400000);             //  6,400,000
    int*            row_ptr = (int*)(ws + 12800000);            //    400,016
    int*            bcnt    = (int*)(ws + 13200016);            //        800
    int*            bbase   = (int*)(ws + 13200816);            //        800
    int*            gcur    = (int*)(ws + 13201616);            //        800
    unsigned short* wp1r    = (unsigned short*)(ws + 13202432); //     32,768
    unsigned short* wp1o    = (unsigned short*)(ws + 13235200); //     32,768
    unsigned short* wp2r    = (unsigned short*)(ws + 13267968); //     65,536
    unsigned short* wp2o    = (unsigned short*)(ws + 13333504); //     65,536
    float*          pooled  = (float*)(ws + 13399040);          //     32,768
    float*          cnts    = (float*)(ws + 13431808);          //        256
    unsigned short* xb      = (unsigned short*)(ws + 13432064); // 12,800,000
    unsigned short* agg1b   = (unsigned short*)(ws + 26232064); // 12,800,000
    unsigned short* h1b     = (unsigned short*)(ws + 39032064); // 25,600,000
    unsigned short* agg2b   = (unsigned short*)(ws + 64632064); // 25,600,000
    float*          h2      = (float*)(ws + 90232064);          // 51,200,000

    hipMemsetAsync(pooled, 0, 33024, stream);   // pooled + cnts
    hipMemsetAsync(bcnt, 0, 800, stream);

    // ---- casts & weight packing ----
    cast_bf16_kernel<<<(N_NODES_C * IN_DIM_C / 4 + 255) / 256, 256, 0, stream>>>(x, xb, N_NODES_C * IN_DIM_C / 4);
    pack_w_kernel<<<(IN_DIM_C / 32) * 8, 64, 0, stream>>>(w1_rel,  wp1r);
    pack_w_kernel<<<(IN_DIM_C / 32) * 8, 64, 0, stream>>>(w1_root, wp1o);
    pack_w_kernel<<<(HID_C  / 32) * 8, 64, 0, stream>>>(w2_rel,  wp2r);
    pack_w_kernel<<<(HID_C  / 32) * 8, 64, 0, stream>>>(w2_root, wp2o);

    // ---- CSR build (bucketed counting sort) ----
    bucket_hist_kernel<<<(N_EDGES_C + 2047) / 2048, 256, 0, stream>>>(ei, bcnt);
    bucket_scan_kernel<<<1, 256, 0, stream>>>(bcnt, bbase, gcur);
    partition_kernel<<<NBLK_A, 256, 0, stream>>>(ei, gcur, tmp);
    bucket_sort_kernel<<<NB_BKT, 256, 0, stream>>>(tmp, bbase, row_ptr, col);

    const int ggrid = (N_NODES_C + 3) / 4;       // 25000
    const int cgrid = (N_NODES_C + 63) / 64;     // 1563

    // ---- Layer 1 ----
    gather_bf64_kernel<<<ggrid, 256, 0, stream>>>(xb, row_ptr, col, agg1b);
    conv_mfma_kernel<IN_DIM_C, IN_DIM_C, false><<<cgrid, 256, 0, stream>>>(
        agg1b, xb, wp1r, wp1o, b1, (void*)h1b, N_NODES_C);

    // ---- Layer 2 ----
    gather_bf128_kernel<<<ggrid, 256, 0, stream>>>(h1b, row_ptr, col, agg2b);
    conv_mfma_kernel<HID_C, HID_C, true><<<cgrid, 256, 0, stream>>>(
        agg2b, h1b, wp2r, wp2o, b2, (void*)h2, N_NODES_C);

    // ---- Pool + head ----
    const int pgrid = (N_NODES_C + 127) / 128;   // 782
    pool_kernel<<<pgrid, 128, 0, stream>>>(h2, batch, pooled, cnts, N_NODES_C);
    head_kernel<<<N_GRAPHS_C, 128, 0, stream>>>(pooled, cnts, fc1w, fc1b, fc2w, fc2b, out);
}

// Round 6
// 348.196 us; speedup vs baseline: 12.4697x; 1.1342x over previous
//
#include <hip/hip_runtime.h>
#include <math.h>

#define N_NODES_C 100000
#define N_EDGES_C 1600000
#define IN_DIM_C 64
#define HID_C 128
#define N_ASSETS_C 50
#define N_GRAPHS_C 64

#define BKT_SHIFT 9
#define BKT_NODES 512
#define NB_BKT ((N_NODES_C + BKT_NODES - 1) / BKT_NODES)   // 196
#define EPB_A 8192
#define NBLK_A ((N_EDGES_C + EPB_A - 1) / EPB_A)            // 196

typedef __attribute__((ext_vector_type(8))) short bf16x8;
typedef __attribute__((ext_vector_type(4))) float f32x4;

__device__ __forceinline__ unsigned short f2bf(float f) {
    unsigned u = __float_as_uint(f);
    return (unsigned short)((u + 0x7FFFu + ((u >> 16) & 1u)) >> 16);
}
__device__ __forceinline__ float bf2f(unsigned short b) {
    return __uint_as_float((unsigned)b << 16);
}
__device__ __forceinline__ void acc_bf8(float* acc, uint4 v) {
    acc[0] += __uint_as_float(v.x << 16);
    acc[1] += __uint_as_float(v.x & 0xFFFF0000u);
    acc[2] += __uint_as_float(v.y << 16);
    acc[3] += __uint_as_float(v.y & 0xFFFF0000u);
    acc[4] += __uint_as_float(v.z << 16);
    acc[5] += __uint_as_float(v.z & 0xFFFF0000u);
    acc[6] += __uint_as_float(v.w << 16);
    acc[7] += __uint_as_float(v.w & 0xFFFF0000u);
}

// ---------------------------------------------------------------------------
// fp32 -> bf16 cast (vectorized), n4 = count/4
// ---------------------------------------------------------------------------
__global__ __launch_bounds__(256) void cast_bf16_kernel(
    const float* __restrict__ src, unsigned short* __restrict__ dst, int n4)
{
    int i = blockIdx.x * 256 + threadIdx.x;
    if (i < n4) {
        float4 v = ((const float4*)src)[i];
        ushort4 o;
        o.x = f2bf(v.x); o.y = f2bf(v.y); o.z = f2bf(v.z); o.w = f2bf(v.w);
        ((ushort4*)dst)[i] = o;
    }
}

// ---------------------------------------------------------------------------
// Pack fp32 weight [Kw x 128] into MFMA B-fragments, split hi/lo bf16.
// ---------------------------------------------------------------------------
__global__ __launch_bounds__(64) void pack_w_kernel(
    const float* __restrict__ W, unsigned short* __restrict__ dst)
{
    int kc = blockIdx.x >> 3;
    int ct = blockIdx.x & 7;
    int lane = threadIdx.x;
    int quad = lane >> 4;
    int l16 = lane & 15;
    unsigned short hi[8], lo[8];
#pragma unroll
    for (int j = 0; j < 8; ++j) {
        float w = W[(size_t)(kc * 32 + quad * 8 + j) * HID_C + ct * 16 + l16];
        unsigned short h = f2bf(w);
        float r = w - bf2f(h);
        hi[j] = h;
        lo[j] = f2bf(r);
    }
    size_t base = ((size_t)(kc * 8 + ct) * 2) * 512 + (size_t)lane * 8;
#pragma unroll
    for (int j = 0; j < 8; ++j) {
        dst[base + j] = hi[j];
        dst[base + 512 + j] = lo[j];
    }
}

// ---------------------------------------------------------------------------
// CSR build: bucketed counting sort.
// ---------------------------------------------------------------------------
__global__ __launch_bounds__(256) void bucket_hist_kernel(
    const int* __restrict__ ei, int* __restrict__ bcnt)
{
    __shared__ int cnt[NB_BKT];
    int t = threadIdx.x;
    for (int i = t; i < NB_BKT; i += 256) cnt[i] = 0;
    __syncthreads();
    int base = blockIdx.x * 2048;
#pragma unroll
    for (int i = 0; i < 8; ++i) {
        int e = base + i * 256 + t;
        if (e < N_EDGES_C) {
            int dst = ei[N_EDGES_C + e];
            atomicAdd(&cnt[dst >> BKT_SHIFT], 1);
        }
    }
    __syncthreads();
    for (int i = t; i < NB_BKT; i += 256)
        if (cnt[i]) atomicAdd(&bcnt[i], cnt[i]);
}

__global__ __launch_bounds__(256) void bucket_scan_kernel(
    const int* __restrict__ bcnt, int* __restrict__ bbase, int* __restrict__ gcur)
{
    __shared__ int s[256];
    int t = threadIdx.x;
    int v = (t < NB_BKT) ? bcnt[t] : 0;
    s[t] = v;
    __syncthreads();
    for (int o = 1; o < 256; o <<= 1) {
        int x = (t >= o) ? s[t - o] : 0;
        __syncthreads();
        s[t] += x;
        __syncthreads();
    }
    int excl = s[t] - v;
    if (t < NB_BKT) { bbase[t] = excl; gcur[t] = excl; }
    if (t == 255) bbase[NB_BKT] = s[255];
}

__global__ __launch_bounds__(256) void partition_kernel(
    const int* __restrict__ ei, int* __restrict__ gcur,
    unsigned* __restrict__ tmp)
{
    __shared__ unsigned stage[EPB_A];
    __shared__ unsigned stage2[EPB_A];
    __shared__ unsigned char sbkt[EPB_A];
    __shared__ unsigned char sbkt2[EPB_A];
    __shared__ int cnt[NB_BKT];
    __shared__ int base[NB_BKT];
    __shared__ int cur[NB_BKT];
    __shared__ int gb[NB_BKT];
    __shared__ int s[256];

    const int t = threadIdx.x;
    const int e0 = blockIdx.x * EPB_A;
    const int nE = min(EPB_A, N_EDGES_C - e0);

    for (int i = t; i < NB_BKT; i += 256) cnt[i] = 0;
    __syncthreads();

    for (int idx = t; idx < nE; idx += 256) {
        int e = e0 + idx;
        int src = ei[e];
        int dst = ei[N_EDGES_C + e];
        int b = dst >> BKT_SHIFT;
        stage[idx] = ((unsigned)(dst & (BKT_NODES - 1)) << 17) | (unsigned)src;
        sbkt[idx] = (unsigned char)b;
        atomicAdd(&cnt[b], 1);
    }
    __syncthreads();

    int v = (t < NB_BKT) ? cnt[t] : 0;
    s[t] = v;
    __syncthreads();
    for (int o = 1; o < 256; o <<= 1) {
        int x = (t >= o) ? s[t - o] : 0;
        __syncthreads();
        s[t] += x;
        __syncthreads();
    }
    if (t < NB_BKT) {
        int excl = s[t] - v;
        base[t] = excl;
        cur[t] = excl;
        gb[t] = atomicAdd(&gcur[t], v);
    }
    __syncthreads();

    for (int idx = t; idx < nE; idx += 256) {
        int b = sbkt[idx];
        int p = atomicAdd(&cur[b], 1);
        stage2[p] = stage[idx];
        sbkt2[p] = (unsigned char)b;
    }
    __syncthreads();

    for (int idx = t; idx < nE; idx += 256) {
        int b = sbkt2[idx];
        int dest = gb[b] + (idx - base[b]);
        tmp[dest] = stage2[idx];
    }
}

__global__ __launch_bounds__(256) void bucket_sort_kernel(
    const unsigned* __restrict__ tmp, const int* __restrict__ bbase,
    int* __restrict__ row_ptr, int* __restrict__ col)
{
    __shared__ int ldeg[BKT_NODES];
    __shared__ int lsum[256];
    const int t = threadIdx.x;
    const int b = blockIdx.x;
    const int beg = bbase[b];
    const int end = bbase[b + 1];

    ldeg[t] = 0; ldeg[t + 256] = 0;
    __syncthreads();

    for (int p = beg + t; p < end; p += 256)
        atomicAdd(&ldeg[tmp[p] >> 17], 1);
    __syncthreads();

    int a0 = ldeg[2 * t], a1 = ldeg[2 * t + 1];
    int pair = a0 + a1;
    lsum[t] = pair;
    __syncthreads();
    for (int o = 1; o < 256; o <<= 1) {
        int x = (t >= o) ? lsum[t - o] : 0;
        __syncthreads();
        lsum[t] += x;
        __syncthreads();
    }
    int ep = lsum[t] - pair;
    __syncthreads();
    ldeg[2 * t] = ep;
    ldeg[2 * t + 1] = ep + a0;

    int gn0 = b * BKT_NODES + 2 * t;
    if (gn0 < N_NODES_C)     row_ptr[gn0] = beg + ep;
    if (gn0 + 1 < N_NODES_C) row_ptr[gn0 + 1] = beg + ep + a0;
    if (b == NB_BKT - 1 && t == 0) row_ptr[N_NODES_C] = N_EDGES_C;
    __syncthreads();

    for (int p = beg + t; p < end; p += 256) {
        unsigned v = tmp[p];
        int pos = atomicAdd(&ldeg[v >> 17], 1);
        col[beg + pos] = (int)(v & 0x1FFFFu);
    }
}

// ---------------------------------------------------------------------------
// Gathers: multi-edge lane groups, dwordx4 loads, shfl_xor reduce.
// W=128: 16-lane groups, up to 4 loads (16 edges) in flight.
// ---------------------------------------------------------------------------
__global__ __launch_bounds__(256) void gather_bf128_kernel(
    const unsigned short* __restrict__ feat, const int* __restrict__ row_ptr,
    const int* __restrict__ col, unsigned short* __restrict__ agg)
{
    int wave = threadIdx.x >> 6;
    int lane = threadIdx.x & 63;
    int g = lane >> 4;     // edge subgroup 0..3
    int c = lane & 15;     // 16B chunk within row (row = 16 x uint4)
    int n = blockIdx.x * 4 + wave;
    if (n >= N_NODES_C) return;
    int beg = row_ptr[n], end = row_ptr[n + 1];
    const uint4* f4 = (const uint4*)feat;

    float acc[8];
#pragma unroll
    for (int j = 0; j < 8; ++j) acc[j] = 0.f;

    int e = beg + g;
    for (; e + 12 < end; e += 16) {
        int s0 = col[e], s1 = col[e + 4], s2 = col[e + 8], s3 = col[e + 12];
        uint4 v0 = f4[(size_t)s0 * 16 + c];
        uint4 v1 = f4[(size_t)s1 * 16 + c];
        uint4 v2 = f4[(size_t)s2 * 16 + c];
        uint4 v3 = f4[(size_t)s3 * 16 + c];
        acc_bf8(acc, v0); acc_bf8(acc, v1); acc_bf8(acc, v2); acc_bf8(acc, v3);
    }
    if (e + 4 < end) {
        int s0 = col[e], s1 = col[e + 4];
        uint4 v0 = f4[(size_t)s0 * 16 + c];
        uint4 v1 = f4[(size_t)s1 * 16 + c];
        acc_bf8(acc, v0); acc_bf8(acc, v1);
        e += 8;
    }
    if (e < end) {
        uint4 v = f4[(size_t)col[e] * 16 + c];
        acc_bf8(acc, v);
    }
#pragma unroll
    for (int j = 0; j < 8; ++j) {
        acc[j] += __shfl_xor(acc[j], 16, 64);
        acc[j] += __shfl_xor(acc[j], 32, 64);
    }
    if (g == 0) {
        uint4 o;
        o.x = (unsigned)f2bf(acc[0]) | ((unsigned)f2bf(acc[1]) << 16);
        o.y = (unsigned)f2bf(acc[2]) | ((unsigned)f2bf(acc[3]) << 16);
        o.z = (unsigned)f2bf(acc[4]) | ((unsigned)f2bf(acc[5]) << 16);
        o.w = (unsigned)f2bf(acc[6]) | ((unsigned)f2bf(acc[7]) << 16);
        ((uint4*)agg)[(size_t)n * 16 + c] = o;
    }
}

__global__ __launch_bounds__(256) void gather_bf64_kernel(
    const unsigned short* __restrict__ feat, const int* __restrict__ row_ptr,
    const int* __restrict__ col, unsigned short* __restrict__ agg)
{
    int wave = threadIdx.x >> 6;
    int lane = threadIdx.x & 63;
    int g = lane >> 3;     // edge subgroup 0..7
    int c = lane & 7;      // 16B chunk within row (row = 8 x uint4)
    int n = blockIdx.x * 4 + wave;
    if (n >= N_NODES_C) return;
    int beg = row_ptr[n], end = row_ptr[n + 1];
    const uint4* f4 = (const uint4*)feat;

    float acc[8];
#pragma unroll
    for (int j = 0; j < 8; ++j) acc[j] = 0.f;

    int e = beg + g;
    for (; e + 8 < end; e += 16) {
        int s0 = col[e], s1 = col[e + 8];
        uint4 v0 = f4[(size_t)s0 * 8 + c];
        uint4 v1 = f4[(size_t)s1 * 8 + c];
        acc_bf8(acc, v0); acc_bf8(acc, v1);
    }
    if (e < end) {
        uint4 v = f4[(size_t)col[e] * 8 + c];
        acc_bf8(acc, v);
    }
#pragma unroll
    for (int j = 0; j < 8; ++j) {
        acc[j] += __shfl_xor(acc[j], 8, 64);
        acc[j] += __shfl_xor(acc[j], 16, 64);
        acc[j] += __shfl_xor(acc[j], 32, 64);
    }
    if (g == 0) {
        uint4 o;
        o.x = (unsigned)f2bf(acc[0]) | ((unsigned)f2bf(acc[1]) << 16);
        o.y = (unsigned)f2bf(acc[2]) | ((unsigned)f2bf(acc[3]) << 16);
        o.z = (unsigned)f2bf(acc[4]) | ((unsigned)f2bf(acc[5]) << 16);
        o.w = (unsigned)f2bf(acc[6]) | ((unsigned)f2bf(acc[7]) << 16);
        ((uint4*)agg)[(size_t)n * 8 + c] = o;
    }
}

// ---------------------------------------------------------------------------
// MFMA conv phase: acc += [P rows] @ [WP hi] + [P rows] @ [WP lo]
// ---------------------------------------------------------------------------
template<int K>
__device__ __forceinline__ void conv_phase(
    const unsigned short* __restrict__ P, const unsigned short* __restrict__ WP,
    const int* rowIdx, int quad, int lane, int wv, f32x4 acc[4][2])
{
#pragma unroll
    for (int kc = 0; kc < K / 32; ++kc) {
        bf16x8 afr[4];
#pragma unroll
        for (int rt = 0; rt < 4; ++rt)
            afr[rt] = *(const bf16x8*)(P + (size_t)rowIdx[rt] * K + kc * 32 + quad * 8);
#pragma unroll
        for (int ci = 0; ci < 2; ++ci) {
            int ct = wv * 2 + ci;
            const unsigned short* bp = WP + ((size_t)(kc * 8 + ct) * 2) * 512 + (size_t)lane * 8;
            bf16x8 bhi = *(const bf16x8*)bp;
            bf16x8 blo = *(const bf16x8*)(bp + 512);
#pragma unroll
            for (int rt = 0; rt < 4; ++rt) {
                acc[rt][ci] = __builtin_amdgcn_mfma_f32_16x16x32_bf16(afr[rt], bhi, acc[rt][ci], 0, 0, 0);
                acc[rt][ci] = __builtin_amdgcn_mfma_f32_16x16x32_bf16(afr[rt], blo, acc[rt][ci], 0, 0, 0);
            }
        }
    }
}

// Layer-1 conv: bf16 out.
template<int KA, int KX>
__global__ __launch_bounds__(256) void conv_mfma_kernel(
    const unsigned short* __restrict__ A, const unsigned short* __restrict__ X,
    const unsigned short* __restrict__ WrP, const unsigned short* __restrict__ WoP,
    const float* __restrict__ bias, unsigned short* __restrict__ outp, int N)
{
    const int t = threadIdx.x;
    const int wv = t >> 6;
    const int lane = t & 63;
    const int quad = lane >> 4;
    const int l16 = lane & 15;
    const int n0 = blockIdx.x * 64;

    f32x4 acc[4][2];
#pragma unroll
    for (int rt = 0; rt < 4; ++rt)
#pragma unroll
        for (int ci = 0; ci < 2; ++ci)
            acc[rt][ci] = (f32x4){0.f, 0.f, 0.f, 0.f};

    int rowIdx[4];
#pragma unroll
    for (int rt = 0; rt < 4; ++rt) {
        int r = n0 + rt * 16 + l16;
        rowIdx[rt] = (r < N) ? r : (N - 1);
    }

    conv_phase<KA>(A, WrP, rowIdx, quad, lane, wv, acc);
    conv_phase<KX>(X, WoP, rowIdx, quad, lane, wv, acc);

#pragma unroll
    for (int ci = 0; ci < 2; ++ci) {
        int colg = wv * 32 + ci * 16 + l16;
        float bv = bias[colg];
#pragma unroll
        for (int rt = 0; rt < 4; ++rt) {
            int nbase = n0 + rt * 16 + quad * 4;
#pragma unroll
            for (int r = 0; r < 4; ++r) {
                int node = nbase + r;
                if (node < N)
                    outp[(size_t)node * HID_C + colg] = f2bf(fmaxf(acc[rt][ci][r] + bv, 0.f));
            }
        }
    }
}

// Layer-2 conv with fused mean-pool partials: h2 never materialized.
template<int KA, int KX>
__global__ __launch_bounds__(256) void conv_mfma_pool_kernel(
    const unsigned short* __restrict__ A, const unsigned short* __restrict__ X,
    const unsigned short* __restrict__ WrP, const unsigned short* __restrict__ WoP,
    const float* __restrict__ bias, const int* __restrict__ batch,
    float* __restrict__ pooled, int N)
{
    __shared__ int sbatch[64];
    const int t = threadIdx.x;
    const int wv = t >> 6;
    const int lane = t & 63;
    const int quad = lane >> 4;
    const int l16 = lane & 15;
    const int n0 = blockIdx.x * 64;

    if (t < 64) {
        int node = n0 + t;
        sbatch[t] = (node < N) ? batch[node] : -1;
    }

    f32x4 acc[4][2];
#pragma unroll
    for (int rt = 0; rt < 4; ++rt)
#pragma unroll
        for (int ci = 0; ci < 2; ++ci)
            acc[rt][ci] = (f32x4){0.f, 0.f, 0.f, 0.f};

    int rowIdx[4];
#pragma unroll
    for (int rt = 0; rt < 4; ++rt) {
        int r = n0 + rt * 16 + l16;
        rowIdx[rt] = (r < N) ? r : (N - 1);
    }

    conv_phase<KA>(A, WrP, rowIdx, quad, lane, wv, acc);
    conv_phase<KX>(X, WoP, rowIdx, quad, lane, wv, acc);
    __syncthreads();

    // bias + relu in place
#pragma unroll
    for (int ci = 0; ci < 2; ++ci) {
        float bv = bias[wv * 32 + ci * 16 + l16];
#pragma unroll
        for (int rt = 0; rt < 4; ++rt)
#pragma unroll
            for (int r = 0; r < 4; ++r)
                acc[rt][ci][r] = fmaxf(acc[rt][ci][r] + bv, 0.f);
    }

    int gmin = sbatch[0];
    int gmax = batch[min(n0 + 63, N - 1)];
    for (int gg = gmin; gg <= gmax; ++gg) {
#pragma unroll
        for (int ci = 0; ci < 2; ++ci) {
            float p = 0.f;
#pragma unroll
            for (int rt = 0; rt < 4; ++rt) {
                int lbase = rt * 16 + quad * 4;
#pragma unroll
                for (int r = 0; r < 4; ++r)
                    if (sbatch[lbase + r] == gg) p += acc[rt][ci][r];
            }
            p += __shfl_xor(p, 16, 64);
            p += __shfl_xor(p, 32, 64);
            if (quad == 0)
                atomicAdd(&pooled[gg * HID_C + wv * 32 + ci * 16 + l16], p);
        }
    }
}

// ---------------------------------------------------------------------------
// Per-graph node counts (batch sorted): run-length per thread, LDS histogram.
// ---------------------------------------------------------------------------
__global__ __launch_bounds__(256) void count_kernel(
    const int* __restrict__ batch, float* __restrict__ cnts, int N)
{
    __shared__ int h[N_GRAPHS_C];
    int t = threadIdx.x;
    if (t < N_GRAPHS_C) h[t] = 0;
    __syncthreads();
    int base = (blockIdx.x * 256 + t) * 16;
    int cur = -1, c = 0;
    for (int i = 0; i < 16; ++i) {
        int n = base + i;
        if (n < N) {
            int g = batch[n];
            if (g != cur) {
                if (cur >= 0) atomicAdd(&h[cur], c);
                cur = g; c = 0;
            }
            ++c;
        }
    }
    if (cur >= 0) atomicAdd(&h[cur], c);
    __syncthreads();
    if (t < N_GRAPHS_C && h[t]) atomicAdd(&cnts[t], (float)h[t]);
}

// ---------------------------------------------------------------------------
// Head: mean, fc1+relu, fc2, softmax (all fp32). One block per graph.
// ---------------------------------------------------------------------------
__global__ __launch_bounds__(128) void head_kernel(
    const float* __restrict__ pooled, const float* __restrict__ cnts,
    const float* __restrict__ fc1w, const float* __restrict__ fc1b,
    const float* __restrict__ fc2w, const float* __restrict__ fc2b,
    float* __restrict__ out)
{
    __shared__ float sp[HID_C];
    __shared__ float so[HID_C];
    __shared__ float sl[64];
    __shared__ float sred[2];
    int g = blockIdx.x;
    int j = threadIdx.x;

    float inv = 1.f / fmaxf(cnts[g], 1.f);
    sp[j] = pooled[g * HID_C + j] * inv;
    __syncthreads();

    float a = fc1b[j];
    for (int k = 0; k < HID_C; ++k) a = fmaf(sp[k], fc1w[k * HID_C + j], a);
    so[j] = fmaxf(a, 0.f);
    __syncthreads();

    if (j < N_ASSETS_C) {
        float l = fc2b[j];
        for (int k = 0; k < HID_C; ++k) l = fmaf(so[k], fc2w[k * N_ASSETS_C + j], l);
        sl[j] = l;
    }
    __syncthreads();

    if (j == 0) {
        float m = -1e30f;
        for (int q = 0; q < N_ASSETS_C; ++q) m = fmaxf(m, sl[q]);
        sred[0] = m;
    }
    __syncthreads();
    if (j < N_ASSETS_C) sl[j] = expf(sl[j] - sred[0]);
    __syncthreads();
    if (j == 0) {
        float s = 0.f;
        for (int q = 0; q < N_ASSETS_C; ++q) s += sl[q];
        sred[1] = 1.f / s;
    }
    __syncthreads();
    if (j < N_ASSETS_C) out[g * N_ASSETS_C + j] = sl[j] * sred[1];
}

// ---------------------------------------------------------------------------
extern "C" void kernel_launch(void* const* d_in, const int* in_sizes, int n_in,
                              void* d_out, int out_size, void* d_ws, size_t ws_size,
                              hipStream_t stream)
{
    const float* x       = (const float*)d_in[0];
    const int*   ei      = (const int*)d_in[1];
    const int*   batch   = (const int*)d_in[2];
    const float* w1_rel  = (const float*)d_in[3];
    const float* b1      = (const float*)d_in[4];
    const float* w1_root = (const float*)d_in[5];
    const float* w2_rel  = (const float*)d_in[6];
    const float* b2      = (const float*)d_in[7];
    const float* w2_root = (const float*)d_in[8];
    const float* fc1w    = (const float*)d_in[9];
    const float* fc1b    = (const float*)d_in[10];
    const float* fc2w    = (const float*)d_in[11];
    const float* fc2b    = (const float*)d_in[12];
    float* out = (float*)d_out;

    char* ws = (char*)d_ws;
    unsigned*       tmp     = (unsigned*)(ws + 0);              //  6,400,000
    int*            col     = (int*)(ws + 6400000);             //  6,400,000
    int*            row_ptr = (int*)(ws + 12800000);            //    400,016
    int*            bcnt    = (int*)(ws + 13200016);            //        800
    int*            bbase   = (int*)(ws + 13200816);            //        800
    int*            gcur    = (int*)(ws + 13201616);            //        800
    unsigned short* wp1r    = (unsigned short*)(ws + 13202432); //     32,768
    unsigned short* wp1o    = (unsigned short*)(ws + 13235200); //     32,768
    unsigned short* wp2r    = (unsigned short*)(ws + 13267968); //     65,536
    unsigned short* wp2o    = (unsigned short*)(ws + 13333504); //     65,536
    float*          pooled  = (float*)(ws + 13399040);          //     32,768
    float*          cnts    = (float*)(ws + 13431808);          //        256
    unsigned short* xb      = (unsigned short*)(ws + 13432064); // 12,800,000
    unsigned short* agg1b   = (unsigned short*)(ws + 26232064); // 12,800,000
    unsigned short* h1b     = (unsigned short*)(ws + 39032064); // 25,600,000
    unsigned short* agg2b   = (unsigned short*)(ws + 64632064); // 25,600,000

    hipMemsetAsync(pooled, 0, 33024, stream);   // pooled + cnts
    hipMemsetAsync(bcnt, 0, 800, stream);

    // ---- casts & weight packing ----
    cast_bf16_kernel<<<(N_NODES_C * IN_DIM_C / 4 + 255) / 256, 256, 0, stream>>>(x, xb, N_NODES_C * IN_DIM_C / 4);
    pack_w_kernel<<<(IN_DIM_C / 32) * 8, 64, 0, stream>>>(w1_rel,  wp1r);
    pack_w_kernel<<<(IN_DIM_C / 32) * 8, 64, 0, stream>>>(w1_root, wp1o);
    pack_w_kernel<<<(HID_C  / 32) * 8, 64, 0, stream>>>(w2_rel,  wp2r);
    pack_w_kernel<<<(HID_C  / 32) * 8, 64, 0, stream>>>(w2_root, wp2o);

    // ---- per-graph counts (independent) ----
    count_kernel<<<(N_NODES_C + 4095) / 4096, 256, 0, stream>>>(batch, cnts, N_NODES_C);

    // ---- CSR build (bucketed counting sort) ----
    bucket_hist_kernel<<<(N_EDGES_C + 2047) / 2048, 256, 0, stream>>>(ei, bcnt);
    bucket_scan_kernel<<<1, 256, 0, stream>>>(bcnt, bbase, gcur);
    partition_kernel<<<NBLK_A, 256, 0, stream>>>(ei, gcur, tmp);
    bucket_sort_kernel<<<NB_BKT, 256, 0, stream>>>(tmp, bbase, row_ptr, col);

    const int ggrid = (N_NODES_C + 3) / 4;       // 25000
    const int cgrid = (N_NODES_C + 63) / 64;     // 1563

    // ---- Layer 1 ----
    gather_bf64_kernel<<<ggrid, 256, 0, stream>>>(xb, row_ptr, col, agg1b);
    conv_mfma_kernel<IN_DIM_C, IN_DIM_C><<<cgrid, 256, 0, stream>>>(
        agg1b, xb, wp1r, wp1o, b1, h1b, N_NODES_C);

    // ---- Layer 2 (pool fused into epilogue) ----
    gather_bf128_kernel<<<ggrid, 256, 0, stream>>>(h1b, row_ptr, col, agg2b);
    conv_mfma_pool_kernel<HID_C, HID_C><<<cgrid, 256, 0, stream>>>(
        agg2b, h1b, wp2r, wp2o, b2, batch, pooled, N_NODES_C);

    // ---- Head ----
    head_kernel<<<N_GRAPHS_C, 128, 0, stream>>>(pooled, cnts, fc1w, fc1b, fc2w, fc2b, out);
}